// Round 4
// baseline (1514.103 us; speedup 1.0000x reference)
//
#include <hip/hip_runtime.h>
#include <hip/hip_bf16.h>
#include <math.h>

#define NODE_DIM 64
#define EDGE_DIM 32
#define HIDDEN   128
#define OUT_DIM  32
#define N_LAYERS 3
#define NGRAPH   128

typedef __attribute__((ext_vector_type(8))) short bf16x8;
typedef __attribute__((ext_vector_type(4))) float f32x4;

__device__ __forceinline__ unsigned short f2bf(float f) {
    unsigned u = __float_as_uint(f);
    u = (u + 0x7fffu + ((u >> 16) & 1u)) >> 16;
    return (unsigned short)u;
}
__device__ __forceinline__ float bf2f(unsigned short h) {
    return __uint_as_float((unsigned)h << 16);
}
// tanh(x) = 2/(1+exp(-2x)) - 1 : saturates correctly at +/-1, no abs/copysign
__device__ __forceinline__ float fast_tanh(float x) {
    float e = __expf(-2.f * x);
    float r = __builtin_amdgcn_rcpf(1.f + e);
    return __builtin_fmaf(2.f, r, -1.f);
}

// ---------------------------------------------------------------------------
// Two-level counting sort of edges by target node — LDS atomics only.
// Coarse bucket = tgt >> 7 (128 nodes per bucket). EPB = 4096 edges/block.
// ---------------------------------------------------------------------------
__global__ __launch_bounds__(256) void coarse_hist_kernel(
    const int* __restrict__ tgt, int* __restrict__ Hc, int E, int C, int NB) {
    __shared__ int lh[512];
    int blk = blockIdx.x, tid = threadIdx.x;
    for (int b = tid; b < C; b += 256) lh[b] = 0;
    __syncthreads();
    int base = blk * 4096;
#pragma unroll
    for (int i = 0; i < 16; ++i) {
        int e = base + i * 256 + tid;
        if (e < E) atomicAdd(&lh[tgt[e] >> 7], 1);
    }
    __syncthreads();
    for (int b = tid; b < C; b += 256) Hc[(size_t)b * NB + blk] = lh[b];
}

// ---------------------------------------------------------------------------
// Hierarchical exclusive scan (3 phases), n up to 256*1024 elements
// ---------------------------------------------------------------------------
__global__ __launch_bounds__(256) void scan1_kernel(const int* __restrict__ c,
                                                    int* __restrict__ o,
                                                    int* __restrict__ bsum, int n) {
    __shared__ int sh[256];
    int b = blockIdx.x, t = threadIdx.x;
    int i = b * 256 + t;
    int v = (i < n) ? c[i] : 0;
    sh[t] = v;
    __syncthreads();
    for (int d = 1; d < 256; d <<= 1) {
        int u = (t >= d) ? sh[t - d] : 0;
        __syncthreads();
        sh[t] += u;
        __syncthreads();
    }
    if (i < n) o[i] = sh[t] - v;          // exclusive within block
    if (t == 255) bsum[b] = sh[255];      // block total
}

__global__ void scan2_kernel(int* __restrict__ bsum, int nb) {
    __shared__ int sh[1024];
    int t = threadIdx.x;
    int v = (t < nb) ? bsum[t] : 0;
    sh[t] = v;
    __syncthreads();
    for (int d = 1; d < 1024; d <<= 1) {
        int u = (t >= d) ? sh[t - d] : 0;
        __syncthreads();
        sh[t] += u;
        __syncthreads();
    }
    if (t < nb) bsum[t] = sh[t] - v;      // exclusive block offsets
}

__global__ __launch_bounds__(256) void scan3_kernel(int* __restrict__ o,
                                                    const int* __restrict__ bsum, int n) {
    int i = blockIdx.x * 256 + threadIdx.x;
    if (i < n) o[i] += bsum[blockIdx.x];
}

__global__ __launch_bounds__(256) void coarse_scatter_kernel(
    const int* __restrict__ tgt, const int* __restrict__ Sc,
    int* __restrict__ tgtc, int* __restrict__ ec, int E, int C, int NB) {
    __shared__ int lb[512];
    int blk = blockIdx.x, tid = threadIdx.x;
    for (int b = tid; b < C; b += 256) lb[b] = Sc[(size_t)b * NB + blk];
    __syncthreads();
    int base = blk * 4096;
#pragma unroll
    for (int i = 0; i < 16; ++i) {
        int e = base + i * 256 + tid;
        if (e < E) {
            int t = tgt[e];
            int pos = atomicAdd(&lb[t >> 7], 1);
            tgtc[pos] = t;
            ec[pos] = e;
        }
    }
}

// One block per coarse bucket: fine 128-bin sort + off[] emission.
__global__ __launch_bounds__(256) void fine_sort_kernel(
    const int* __restrict__ Sc, const int* __restrict__ tgtc,
    const int* __restrict__ ec, const int* __restrict__ src,
    int* __restrict__ off, int* __restrict__ eidx, int* __restrict__ srcp,
    int E, int N, int C, int NB) {
    __shared__ int fh[128], fs[128], rb[128];
    int b = blockIdx.x, tid = threadIdx.x;
    int cb0 = Sc[(size_t)b * NB];
    int cb1 = (b + 1 < C) ? Sc[(size_t)(b + 1) * NB] : E;
    if (tid < 128) fh[tid] = 0;
    __syncthreads();
    for (int p = cb0 + tid; p < cb1; p += 256) atomicAdd(&fh[tgtc[p] & 127], 1);
    __syncthreads();
    if (tid < 128) fs[tid] = fh[tid];
    __syncthreads();
    for (int d = 1; d < 128; d <<= 1) {
        int v = 0;
        if (tid < 128 && tid >= d) v = fs[tid - d];
        __syncthreads();
        if (tid < 128) fs[tid] += v;
        __syncthreads();
    }
    if (tid < 128) {
        int ex = fs[tid] - fh[tid];  // exclusive base within bucket
        rb[tid] = ex;
        int node = (b << 7) + tid;
        if (node < N) off[node] = cb0 + ex;
    }
    if (b == C - 1 && tid == 0) off[N] = E;
    __syncthreads();
    for (int p = cb0 + tid; p < cb1; p += 256) {
        int t = tgtc[p];
        int r = atomicAdd(&rb[t & 127], 1);
        int fpos = cb0 + r;
        int e = ec[p];
        eidx[fpos] = e;
        srcp[fpos] = src[e];
    }
}

// batch is sorted: mark graph boundaries directly
__global__ void gbound_kernel(const int* __restrict__ batch, int* __restrict__ goff,
                              int N, int G) {
    int i = blockIdx.x * 256 + threadIdx.x;
    if (i >= N) return;
    int b = batch[i];
    if (i == 0) {
        for (int g = 0; g <= b; ++g) goff[g] = 0;
    } else {
        int bp = batch[i - 1];
        for (int g = bp + 1; g <= b; ++g) goff[g] = i;
    }
    if (i == N - 1) {
        for (int g = b + 1; g <= G; ++g) goff[g] = N;
    }
}

// ---------------------------------------------------------------------------
// Permute+convert edge_attr to bf16 in target-sorted order (coalesced writes)
// ---------------------------------------------------------------------------
__global__ __launch_bounds__(256) void perm_ea_kernel(
    const float* __restrict__ ea, const int* __restrict__ eidx,
    unsigned short* __restrict__ out, int E) {
    int p = blockIdx.x * 256 + threadIdx.x;
    if (p >= E) return;
    int e = eidx[p];
    const float4* r = (const float4*)(ea + (size_t)e * EDGE_DIM);
    union { unsigned short us[EDGE_DIM]; uint4 u4[EDGE_DIM / 8]; } tmp;
#pragma unroll
    for (int q = 0; q < EDGE_DIM / 4; ++q) {
        float4 v = r[q];
        tmp.us[4 * q]     = f2bf(v.x);
        tmp.us[4 * q + 1] = f2bf(v.y);
        tmp.us[4 * q + 2] = f2bf(v.z);
        tmp.us[4 * q + 3] = f2bf(v.w);
    }
    uint4* o = (uint4*)(out + (size_t)p * EDGE_DIM);
#pragma unroll
    for (int k = 0; k < EDGE_DIM / 8; ++k) o[k] = tmp.u4[k];
}

// ---------------------------------------------------------------------------
// Parallel weight swizzle into MFMA A-frag order: one block per 16x32 tile.
// 56 tiles/layer: [0,8) fW1, [8,24) fW2, [24,40) oW1, [40,56) oW2.
// ---------------------------------------------------------------------------
__global__ void swizzle_w_kernel(const float* __restrict__ fW1, const float* __restrict__ fW2,
                                 const float* __restrict__ oW1, const float* __restrict__ oW2,
                                 unsigned short* __restrict__ W1sw, unsigned short* __restrict__ W2sw,
                                 unsigned short* __restrict__ oW1sw, unsigned short* __restrict__ oW2sw) {
    int i = blockIdx.x / 56, r = blockIdx.x % 56;
    int L = threadIdx.x;
    int e = L & 15, q = L >> 4;
    const float* W;
    unsigned short* out;
    int K, M, t;
    if (r < 8)       { W = fW1 + (size_t)i * EDGE_DIM * HIDDEN;  out = W1sw  + (size_t)i * 8 * 512;  K = EDGE_DIM; M = HIDDEN;   t = r; }
    else if (r < 24) { W = fW2 + (size_t)i * HIDDEN * NODE_DIM;  out = W2sw  + (size_t)i * 16 * 512; K = HIDDEN;   M = NODE_DIM; t = r - 8; }
    else if (r < 40) { W = oW1 + (size_t)i * NODE_DIM * HIDDEN;  out = oW1sw + (size_t)i * 16 * 512; K = NODE_DIM; M = HIDDEN;   t = r - 24; }
    else             { W = oW2 + (size_t)i * HIDDEN * NODE_DIM;  out = oW2sw + (size_t)i * 16 * 512; K = HIDDEN;   M = NODE_DIM; t = r - 40; }
    int nc = K >> 5;
    int mt = t / nc, s = t - mt * nc;
    union { unsigned short us[8]; uint4 u4; } pk;
#pragma unroll
    for (int j = 0; j < 8; ++j)
        pk.us[j] = f2bf(W[(size_t)(32 * s + 8 * q + j) * M + 16 * mt + e]);
    *(uint4*)(out + ((size_t)t * 64 + L) * 8) = pk.u4;
}

#define HSTRIDE 136  // shorts; 128 + 8 pad, keeps 16B alignment for ds_read_b128

// ---------------------------------------------------------------------------
// Per-16-edge-group pipeline: MFMA1 interleaved with tanh (sub-rounds of 4
// tiles -> peak 16 acc regs), early hd gather, MFMA2 split into nt-pairs
// (peak 8 acc regs). Keeps total VGPR+AGPR ~<=102 for 5 waves/SIMD.
// ---------------------------------------------------------------------------
__device__ __forceinline__ void eg_process(
    bf16x8 eaf, int sidx, int pdst, bool valid,
    unsigned short* hrow, int lane, int q,
    const unsigned short* __restrict__ W1sw, const float* __restrict__ b1,
    const unsigned short* __restrict__ W2sw, const float* __restrict__ b2,
    const float* __restrict__ av, const float* __restrict__ hd,
    unsigned short* __restrict__ msg, float* __restrict__ score) {
    // ---- phase 1: hidden = tanh(ea @ W1 + b1), staged bf16 in LDS ----
#pragma unroll
    for (int th = 0; th < 2; ++th) {
        f32x4 c[4];
#pragma unroll
        for (int t = 0; t < 4; ++t) {
            bf16x8 a = *(const bf16x8*)(W1sw + ((th * 4 + t) * 64 + lane) * 8);
            c[t] = __builtin_amdgcn_mfma_f32_16x16x32_bf16(a, eaf, (f32x4){0.f, 0.f, 0.f, 0.f}, 0, 0, 0);
        }
#pragma unroll
        for (int t = 0; t < 4; ++t) {
            int tt = th * 4 + t;
            float4 b = *(const float4*)(b1 + 16 * tt + 4 * q);
            unsigned h0 = f2bf(fast_tanh(c[t][0] + b.x));
            unsigned h1 = f2bf(fast_tanh(c[t][1] + b.y));
            unsigned h2 = f2bf(fast_tanh(c[t][2] + b.z));
            unsigned h3 = f2bf(fast_tanh(c[t][3] + b.w));
            uint2 pk;
            pk.x = h0 | (h1 << 16);
            pk.y = h2 | (h3 << 16);
            *(uint2*)(hrow + 16 * tt + 4 * q) = pk;  // ds_write_b64
        }
    }

    // ---- early gather: hd[src] in flight while MFMA2 runs ----
    float4 hv[4];
#pragma unroll
    for (int nt = 0; nt < 4; ++nt)
        hv[nt] = *(const float4*)(hd + (size_t)sidx * NODE_DIM + 16 * nt + 4 * q);

    // ---- phase 2: ew = hidden @ W2, nt-pairs; tail fused per pair ----
    float sc = 0.f;
#pragma unroll
    for (int np = 0; np < 2; ++np) {
        f32x4 c2[2] = {{0.f, 0.f, 0.f, 0.f}, {0.f, 0.f, 0.f, 0.f}};
#pragma unroll
        for (int s = 0; s < 4; ++s) {
            bf16x8 hf = *(const bf16x8*)(hrow + 32 * s + 8 * q);
            bf16x8 a0 = *(const bf16x8*)(W2sw + (((2 * np + 0) * 4 + s) * 64 + lane) * 8);
            bf16x8 a1 = *(const bf16x8*)(W2sw + (((2 * np + 1) * 4 + s) * 64 + lane) * 8);
            c2[0] = __builtin_amdgcn_mfma_f32_16x16x32_bf16(a0, hf, c2[0], 0, 0, 0);
            c2[1] = __builtin_amdgcn_mfma_f32_16x16x32_bf16(a1, hf, c2[1], 0, 0, 0);
        }
#pragma unroll
        for (int k = 0; k < 2; ++k) {
            int nt = 2 * np + k;
            float4 bb = *(const float4*)(b2 + 16 * nt + 4 * q);
            float4 vv = *(const float4*)(av + 16 * nt + 4 * q);
            float4 hh = hv[nt];
            float m0 = (c2[k][0] + bb.x) * hh.x;
            float m1 = (c2[k][1] + bb.y) * hh.y;
            float m2 = (c2[k][2] + bb.z) * hh.z;
            float m3 = (c2[k][3] + bb.w) * hh.w;
            uint2 pk;
            pk.x = (unsigned)f2bf(m0) | ((unsigned)f2bf(m1) << 16);
            pk.y = (unsigned)f2bf(m2) | ((unsigned)f2bf(m3) << 16);
            if (valid) *(uint2*)(msg + (size_t)pdst * NODE_DIM + 16 * nt + 4 * q) = pk;
            sc += m0 * vv.x + m1 * vv.y + m2 * vv.z + m3 * vv.w;
        }
    }
    sc += __shfl_xor(sc, 16, 64);
    sc += __shfl_xor(sc, 32, 64);
    if (q == 0 && valid) score[pdst] = sc;
}

// ---------------------------------------------------------------------------
// MFMA edge kernel: wave per 32 edges, two sequential 16-edge groups sharing
// one LDS H buffer (17.4 KB/block). Register-lean for >=5 waves/SIMD.
// ---------------------------------------------------------------------------
__global__ __launch_bounds__(256, 5) void edge_mfma_kernel(
    const unsigned short* __restrict__ ea_p, const float* __restrict__ hd,
    const unsigned short* __restrict__ W1sw, const float* __restrict__ b1,
    const unsigned short* __restrict__ W2sw, const float* __restrict__ b2,
    const float* __restrict__ av, const int* __restrict__ srcp,
    unsigned short* __restrict__ msg, float* __restrict__ score, int E) {
    __shared__ unsigned short Hl[4][16 * HSTRIDE];
    int wave = threadIdx.x >> 6, lane = threadIdx.x & 63;
    int e = lane & 15, q = lane >> 4;
    int p0 = blockIdx.x * 128 + wave * 32;
    if (p0 >= E) return;
    int pA = p0 + e, pB = p0 + 16 + e;
    int pAc = pA < E ? pA : E - 1;
    int pBc = pB < E ? pB : E - 1;
    bool vA = pA < E, vB = pB < E;

    bf16x8 eafA = *(const bf16x8*)(ea_p + (size_t)pAc * EDGE_DIM + q * 8);
    bf16x8 eafB = *(const bf16x8*)(ea_p + (size_t)pBc * EDGE_DIM + q * 8);
    int sA = srcp[pAc];
    int sB = srcp[pBc];
    unsigned short* hrow = &Hl[wave][e * HSTRIDE];

    eg_process(eafA, sA, pA, vA, hrow, lane, q, W1sw, b1, W2sw, b2, av, hd, msg, score);
    eg_process(eafB, sB, pB, vB, hrow, lane, q, W1sw, b1, W2sw, b2, av, hd, msg, score);
}

// ---------------------------------------------------------------------------
// Fused node out-MLP (MFMA): delta = tanh(agg@oW1+b1)@oW2+b2; h += delta
// ---------------------------------------------------------------------------
__global__ __launch_bounds__(256) void node_mlp_kernel(
    const float* __restrict__ agg,
    const unsigned short* __restrict__ W1sw, const float* __restrict__ b1,
    const unsigned short* __restrict__ W2sw, const float* __restrict__ b2,
    float* __restrict__ h, int N) {
    __shared__ unsigned short Hl[4][16 * HSTRIDE];
    int wave = threadIdx.x >> 6, lane = threadIdx.x & 63;
    int e = lane & 15, q = lane >> 4;
    int n0 = (blockIdx.x * 4 + wave) * 16;
    if (n0 >= N) return;
    int ne = n0 + e;
    int neC = ne < N ? ne : N - 1;
    bool ok = ne < N;

    bf16x8 bfr[2];
#pragma unroll
    for (int s = 0; s < 2; ++s) {
        const float4* ar = (const float4*)(agg + (size_t)neC * NODE_DIM + 32 * s + 8 * q);
        float4 x0 = ar[0], x1 = ar[1];
        union { bf16x8 v; unsigned short us[8]; } u;
        u.us[0] = f2bf(x0.x); u.us[1] = f2bf(x0.y);
        u.us[2] = f2bf(x0.z); u.us[3] = f2bf(x0.w);
        u.us[4] = f2bf(x1.x); u.us[5] = f2bf(x1.y);
        u.us[6] = f2bf(x1.z); u.us[7] = f2bf(x1.w);
        bfr[s] = u.v;
    }

    f32x4 c1[8];
#pragma unroll
    for (int t = 0; t < 8; ++t) {
        bf16x8 a0 = *(const bf16x8*)(W1sw + ((t * 2 + 0) * 64 + lane) * 8);
        bf16x8 a1 = *(const bf16x8*)(W1sw + ((t * 2 + 1) * 64 + lane) * 8);
        c1[t] = __builtin_amdgcn_mfma_f32_16x16x32_bf16(a0, bfr[0], (f32x4){0.f, 0.f, 0.f, 0.f}, 0, 0, 0);
        c1[t] = __builtin_amdgcn_mfma_f32_16x16x32_bf16(a1, bfr[1], c1[t], 0, 0, 0);
    }

    unsigned short* hrow = &Hl[wave][e * HSTRIDE];
#pragma unroll
    for (int t = 0; t < 8; ++t) {
        float4 b = *(const float4*)(b1 + 16 * t + 4 * q);
        unsigned h0 = f2bf(fast_tanh(c1[t][0] + b.x));
        unsigned h1 = f2bf(fast_tanh(c1[t][1] + b.y));
        unsigned h2 = f2bf(fast_tanh(c1[t][2] + b.z));
        unsigned h3 = f2bf(fast_tanh(c1[t][3] + b.w));
        uint2 pk;
        pk.x = h0 | (h1 << 16);
        pk.y = h2 | (h3 << 16);
        *(uint2*)(hrow + 16 * t + 4 * q) = pk;
    }

    f32x4 c2[4] = {{0.f, 0.f, 0.f, 0.f}, {0.f, 0.f, 0.f, 0.f},
                   {0.f, 0.f, 0.f, 0.f}, {0.f, 0.f, 0.f, 0.f}};
#pragma unroll
    for (int s = 0; s < 4; ++s) {
        bf16x8 hf = *(const bf16x8*)(hrow + 32 * s + 8 * q);
#pragma unroll
        for (int nt = 0; nt < 4; ++nt) {
            bf16x8 a = *(const bf16x8*)(W2sw + ((nt * 4 + s) * 64 + lane) * 8);
            c2[nt] = __builtin_amdgcn_mfma_f32_16x16x32_bf16(a, hf, c2[nt], 0, 0, 0);
        }
    }

    if (ok) {
#pragma unroll
        for (int nt = 0; nt < 4; ++nt) {
            float4 bb = *(const float4*)(b2 + 16 * nt + 4 * q);
            float4* hp = (float4*)(h + (size_t)ne * NODE_DIM + 16 * nt + 4 * q);
            float4 hv = *hp;
            hv.x += c2[nt][0] + bb.x;
            hv.y += c2[nt][1] + bb.y;
            hv.z += c2[nt][2] + bb.z;
            hv.w += c2[nt][3] + bb.w;
            *hp = hv;
        }
    }
}

// ---------------------------------------------------------------------------
// Generic dense layer (fp32): hd and final output MLP
// ---------------------------------------------------------------------------
template <int K, int M, bool ACT, bool RESID>
__global__ __launch_bounds__(256) void dense_kernel(
    const float* __restrict__ X, const float* __restrict__ W,
    const float* __restrict__ bias, float* __restrict__ Y, int rows) {
    int tid = blockIdx.x * 256 + threadIdx.x;
    int row = tid / M;
    int d = tid - row * M;
    if (row >= rows) return;
    if (M >= 64) row = __builtin_amdgcn_readfirstlane(row);
    const float* __restrict__ x = X + (size_t)row * K;
    float acc = bias ? bias[d] : 0.f;
#pragma unroll
    for (int k = 0; k < K; ++k) acc += x[k] * W[k * M + d];
    if (ACT) acc = fast_tanh(acc);
    if (RESID) acc += Y[(size_t)row * M + d];
    Y[(size_t)row * M + d] = acc;
}

// ---------------------------------------------------------------------------
// Aggregation: wave per node; single streaming pass (no-max softmax, no gather)
// ---------------------------------------------------------------------------
__global__ __launch_bounds__(256) void agg_kernel(
    const unsigned short* __restrict__ msg, const float* __restrict__ score,
    const int* __restrict__ off, float* __restrict__ agg, int n) {
    int tid = blockIdx.x * 256 + threadIdx.x;
    int wid = tid >> 6;
    int lane = threadIdx.x & 63;
    if (wid >= n) return;
    wid = __builtin_amdgcn_readfirstlane(wid);
    int o0 = off[wid], o1 = off[wid + 1];
    int g = lane >> 3, s = lane & 7;
    if (o1 <= o0) {
        if (g == 0) {
            float4 z = {0.f, 0.f, 0.f, 0.f};
            float4* dst = (float4*)(agg + (size_t)wid * NODE_DIM + s * 8);
            dst[0] = z; dst[1] = z;
        }
        return;
    }
    float den = 0.f;
    float acc[8] = {0.f, 0.f, 0.f, 0.f, 0.f, 0.f, 0.f, 0.f};
    for (int p = o0; p < o1; p += 8) {
        int pe = p + g;
        int pc = (pe < o1) ? pe : (o1 - 1);
        float w = (pe < o1) ? __expf(fminf(score[pc], 60.f)) : 0.f;
        den += w;
        union { bf16x8 v; unsigned short us[8]; } eu;
        eu.v = *(const bf16x8*)(msg + (size_t)pc * NODE_DIM + s * 8);
        acc[0] += w * bf2f(eu.us[0]);
        acc[1] += w * bf2f(eu.us[1]);
        acc[2] += w * bf2f(eu.us[2]);
        acc[3] += w * bf2f(eu.us[3]);
        acc[4] += w * bf2f(eu.us[4]);
        acc[5] += w * bf2f(eu.us[5]);
        acc[6] += w * bf2f(eu.us[6]);
        acc[7] += w * bf2f(eu.us[7]);
    }
    // reduce across the 8 g-groups (lanes within a g-group hold identical den)
#pragma unroll
    for (int j = 0; j < 8; ++j) {
        acc[j] += __shfl_xor(acc[j], 8, 64);
        acc[j] += __shfl_xor(acc[j], 16, 64);
        acc[j] += __shfl_xor(acc[j], 32, 64);
    }
    den += __shfl_xor(den, 8, 64);
    den += __shfl_xor(den, 16, 64);
    den += __shfl_xor(den, 32, 64);
    if (g == 0) {
        float inv = __builtin_amdgcn_rcpf(den);
        inv = inv * (2.f - den * inv);
        float4 r0 = {acc[0] * inv, acc[1] * inv, acc[2] * inv, acc[3] * inv};
        float4 r1 = {acc[4] * inv, acc[5] * inv, acc[6] * inv, acc[7] * inv};
        float4* dst = (float4*)(agg + (size_t)wid * NODE_DIM + s * 8);
        dst[0] = r0; dst[1] = r1;
    }
}

// ---------------------------------------------------------------------------
// Mean pool per graph: 4 waves per graph + LDS reduce
// ---------------------------------------------------------------------------
__global__ __launch_bounds__(256) void pool_kernel(const float* __restrict__ h,
                                                   const int* __restrict__ goff,
                                                   float* __restrict__ pooled) {
    __shared__ float sh[4][NODE_DIM];
    int g = blockIdx.x;
    int w = threadIdx.x >> 6, d = threadIdx.x & 63;
    int o0 = goff[g], o1 = goff[g + 1];
    float acc = 0.f;
    for (int n = o0 + w; n < o1; n += 4) acc += h[(size_t)n * NODE_DIM + d];
    sh[w][d] = acc;
    __syncthreads();
    if (w == 0) {
        float sum = sh[0][d] + sh[1][d] + sh[2][d] + sh[3][d];
        int c = o1 - o0;
        if (c < 1) c = 1;
        pooled[g * NODE_DIM + d] = sum / (float)c;
    }
}

// ---------------------------------------------------------------------------
extern "C" void kernel_launch(void* const* d_in, const int* in_sizes, int n_in,
                              void* d_out, int out_size, void* d_ws, size_t ws_size,
                              hipStream_t stream) {
    const float* x         = (const float*)d_in[0];
    const float* edge_attr = (const float*)d_in[1];
    const int*   ei        = (const int*)d_in[2];
    const int*   batch     = (const int*)d_in[3];
    const float* Wd        = (const float*)d_in[4];
    const float* fW1       = (const float*)d_in[5];
    const float* fb1       = (const float*)d_in[6];
    const float* fW2       = (const float*)d_in[7];
    const float* fb2       = (const float*)d_in[8];
    const float* av        = (const float*)d_in[9];
    const float* oW1       = (const float*)d_in[10];
    const float* ob1       = (const float*)d_in[11];
    const float* oW2       = (const float*)d_in[12];
    const float* ob2       = (const float*)d_in[13];
    const float* nW1       = (const float*)d_in[14];
    const float* nb1       = (const float*)d_in[15];
    const float* nW2       = (const float*)d_in[16];
    const float* nb2       = (const float*)d_in[17];
    float* out = (float*)d_out;

    const int N = in_sizes[0] / NODE_DIM;   // 50000
    const int E = in_sizes[2] / 2;          // 800000
    const int G = NGRAPH;
    const int NB = (E + 4095) / 4096;       // coarse blocks (196)
    const int C  = (N + 127) >> 7;          // coarse buckets (391)
    const int SN = C * NB;                  // scan length (76636)
    const int SB = (SN + 255) / 256;        // scan blocks (300, must be <=1024)

    char* base = (char*)d_ws;
    size_t pos = 0;
    auto alloc = [&](size_t bytes) -> void* {
        pos = (pos + 255) & ~(size_t)255;
        void* r = base + pos;
        pos += bytes;
        return r;
    };
    int* Hc   = (int*)alloc((size_t)SN * 4);
    int* Sc   = (int*)alloc(((size_t)SN + 1) * 4);
    int* bsum = (int*)alloc((size_t)1024 * 4);
    int* tgtc = (int*)alloc((size_t)E * 4);
    int* ec   = (int*)alloc((size_t)E * 4);
    int* off  = (int*)alloc((size_t)(N + 1) * 4);
    int* goff = (int*)alloc((size_t)(G + 1) * 4);
    int* eidx = (int*)alloc((size_t)E * 4);
    int* srcp = (int*)alloc((size_t)E * 4);
    float* score = (float*)alloc((size_t)E * 4);
    float* hd    = (float*)alloc((size_t)N * NODE_DIM * 4);
    float* h     = (float*)alloc((size_t)N * NODE_DIM * 4);
    float* agg   = (float*)alloc((size_t)N * NODE_DIM * 4);
    float* pooled = (float*)alloc((size_t)G * NODE_DIM * 4);
    float* t2     = (float*)alloc((size_t)G * HIDDEN * 4);
    unsigned short* ea_p  = (unsigned short*)alloc((size_t)E * EDGE_DIM * 2);
    unsigned short* msg   = (unsigned short*)alloc((size_t)E * NODE_DIM * 2);
    unsigned short* W1sw  = (unsigned short*)alloc((size_t)N_LAYERS * 8 * 512 * 2);
    unsigned short* W2sw  = (unsigned short*)alloc((size_t)N_LAYERS * 16 * 512 * 2);
    unsigned short* oW1sw = (unsigned short*)alloc((size_t)N_LAYERS * 16 * 512 * 2);
    unsigned short* oW2sw = (unsigned short*)alloc((size_t)N_LAYERS * 16 * 512 * 2);
    (void)ws_size;

    const int* src = ei;
    const int* tgt = ei + E;

    // --- prep: two-level counting sort, hierarchical scan (no global atomics) ---
    coarse_hist_kernel<<<NB, 256, 0, stream>>>(tgt, Hc, E, C, NB);
    scan1_kernel<<<SB, 256, 0, stream>>>(Hc, Sc, bsum, SN);
    scan2_kernel<<<1, 1024, 0, stream>>>(bsum, SB);
    scan3_kernel<<<SB, 256, 0, stream>>>(Sc, bsum, SN);
    coarse_scatter_kernel<<<NB, 256, 0, stream>>>(tgt, Sc, tgtc, ec, E, C, NB);
    fine_sort_kernel<<<C, 256, 0, stream>>>(Sc, tgtc, ec, src, off, eidx, srcp, E, N, C, NB);
    gbound_kernel<<<(N + 255) / 256, 256, 0, stream>>>(batch, goff, N, G);
    perm_ea_kernel<<<(E + 255) / 256, 256, 0, stream>>>(edge_attr, eidx, ea_p, E);
    swizzle_w_kernel<<<N_LAYERS * 56, 64, 0, stream>>>(fW1, fW2, oW1, oW2, W1sw, W2sw, oW1sw, oW2sw);
    hipMemcpyAsync(h, x, (size_t)N * NODE_DIM * 4, hipMemcpyDeviceToDevice, stream);

    const int node_tiles = (N + 15) / 16;
    for (int i = 0; i < N_LAYERS; ++i) {
        dense_kernel<NODE_DIM, NODE_DIM, false, false>
            <<<(N * NODE_DIM + 255) / 256, 256, 0, stream>>>(
                h, Wd + (size_t)i * NODE_DIM * NODE_DIM, nullptr, hd, N);
        edge_mfma_kernel<<<(E + 127) / 128, 256, 0, stream>>>(
            ea_p, hd,
            W1sw + (size_t)i * 8 * 512, fb1 + (size_t)i * HIDDEN,
            W2sw + (size_t)i * 16 * 512, fb2 + (size_t)i * NODE_DIM,
            av + (size_t)i * NODE_DIM, srcp, msg, score, E);
        agg_kernel<<<(N + 3) / 4, 256, 0, stream>>>(msg, score, off, agg, N);
        node_mlp_kernel<<<(node_tiles + 3) / 4, 256, 0, stream>>>(
            agg,
            oW1sw + (size_t)i * 16 * 512, ob1 + (size_t)i * HIDDEN,
            oW2sw + (size_t)i * 16 * 512, ob2 + (size_t)i * NODE_DIM,
            h, N);
    }

    pool_kernel<<<G, 256, 0, stream>>>(h, goff, pooled);
    dense_kernel<NODE_DIM, HIDDEN, true, false>
        <<<(G * HIDDEN + 255) / 256, 256, 0, stream>>>(pooled, nW1, nb1, t2, G);
    dense_kernel<HIDDEN, OUT_DIM, false, false>
        <<<(G * OUT_DIM + 255) / 256, 256, 0, stream>>>(t2, nW2, nb2, out, G);
}

// Round 5
// 776.646 us; speedup vs baseline: 1.9495x; 1.9495x over previous
//
#include <hip/hip_runtime.h>
#include <hip/hip_bf16.h>
#include <math.h>

#define NODE_DIM 64
#define EDGE_DIM 32
#define HIDDEN   128
#define OUT_DIM  32
#define N_LAYERS 3
#define NGRAPH   128

typedef __attribute__((ext_vector_type(8))) short bf16x8;
typedef __attribute__((ext_vector_type(4))) float f32x4;

__device__ __forceinline__ unsigned short f2bf(float f) {
    unsigned u = __float_as_uint(f);
    u = (u + 0x7fffu + ((u >> 16) & 1u)) >> 16;
    return (unsigned short)u;
}
__device__ __forceinline__ float bf2f(unsigned short h) {
    return __uint_as_float((unsigned)h << 16);
}
// tanh(x) = 2/(1+exp(-2x)) - 1 : saturates correctly at +/-1, no abs/copysign
__device__ __forceinline__ float fast_tanh(float x) {
    float e = __expf(-2.f * x);
    float r = __builtin_amdgcn_rcpf(1.f + e);
    return __builtin_fmaf(2.f, r, -1.f);
}

// ---------------------------------------------------------------------------
// Two-level counting sort of edges by target node — LDS atomics only.
// Coarse bucket = tgt >> 7 (128 nodes per bucket). EPB = 4096 edges/block.
// ---------------------------------------------------------------------------
__global__ __launch_bounds__(256) void coarse_hist_kernel(
    const int* __restrict__ tgt, int* __restrict__ Hc, int E, int C, int NB) {
    __shared__ int lh[512];
    int blk = blockIdx.x, tid = threadIdx.x;
    for (int b = tid; b < C; b += 256) lh[b] = 0;
    __syncthreads();
    int base = blk * 4096;
#pragma unroll
    for (int i = 0; i < 16; ++i) {
        int e = base + i * 256 + tid;
        if (e < E) atomicAdd(&lh[tgt[e] >> 7], 1);
    }
    __syncthreads();
    for (int b = tid; b < C; b += 256) Hc[(size_t)b * NB + blk] = lh[b];
}

// ---------------------------------------------------------------------------
// Hierarchical exclusive scan (3 phases), n up to 256*1024 elements
// ---------------------------------------------------------------------------
__global__ __launch_bounds__(256) void scan1_kernel(const int* __restrict__ c,
                                                    int* __restrict__ o,
                                                    int* __restrict__ bsum, int n) {
    __shared__ int sh[256];
    int b = blockIdx.x, t = threadIdx.x;
    int i = b * 256 + t;
    int v = (i < n) ? c[i] : 0;
    sh[t] = v;
    __syncthreads();
    for (int d = 1; d < 256; d <<= 1) {
        int u = (t >= d) ? sh[t - d] : 0;
        __syncthreads();
        sh[t] += u;
        __syncthreads();
    }
    if (i < n) o[i] = sh[t] - v;          // exclusive within block
    if (t == 255) bsum[b] = sh[255];      // block total
}

__global__ void scan2_kernel(int* __restrict__ bsum, int nb) {
    __shared__ int sh[1024];
    int t = threadIdx.x;
    int v = (t < nb) ? bsum[t] : 0;
    sh[t] = v;
    __syncthreads();
    for (int d = 1; d < 1024; d <<= 1) {
        int u = (t >= d) ? sh[t - d] : 0;
        __syncthreads();
        sh[t] += u;
        __syncthreads();
    }
    if (t < nb) bsum[t] = sh[t] - v;      // exclusive block offsets
}

__global__ __launch_bounds__(256) void scan3_kernel(int* __restrict__ o,
                                                    const int* __restrict__ bsum, int n) {
    int i = blockIdx.x * 256 + threadIdx.x;
    if (i < n) o[i] += bsum[blockIdx.x];
}

__global__ __launch_bounds__(256) void coarse_scatter_kernel(
    const int* __restrict__ tgt, const int* __restrict__ Sc,
    int* __restrict__ tgtc, int* __restrict__ ec, int E, int C, int NB) {
    __shared__ int lb[512];
    int blk = blockIdx.x, tid = threadIdx.x;
    for (int b = tid; b < C; b += 256) lb[b] = Sc[(size_t)b * NB + blk];
    __syncthreads();
    int base = blk * 4096;
#pragma unroll
    for (int i = 0; i < 16; ++i) {
        int e = base + i * 256 + tid;
        if (e < E) {
            int t = tgt[e];
            int pos = atomicAdd(&lb[t >> 7], 1);
            tgtc[pos] = t;
            ec[pos] = e;
        }
    }
}

// One block per coarse bucket: fine 128-bin sort + off[] emission.
__global__ __launch_bounds__(256) void fine_sort_kernel(
    const int* __restrict__ Sc, const int* __restrict__ tgtc,
    const int* __restrict__ ec, const int* __restrict__ src,
    int* __restrict__ off, int* __restrict__ eidx, int* __restrict__ srcp,
    int E, int N, int C, int NB) {
    __shared__ int fh[128], fs[128], rb[128];
    int b = blockIdx.x, tid = threadIdx.x;
    int cb0 = Sc[(size_t)b * NB];
    int cb1 = (b + 1 < C) ? Sc[(size_t)(b + 1) * NB] : E;
    if (tid < 128) fh[tid] = 0;
    __syncthreads();
    for (int p = cb0 + tid; p < cb1; p += 256) atomicAdd(&fh[tgtc[p] & 127], 1);
    __syncthreads();
    if (tid < 128) fs[tid] = fh[tid];
    __syncthreads();
    for (int d = 1; d < 128; d <<= 1) {
        int v = 0;
        if (tid < 128 && tid >= d) v = fs[tid - d];
        __syncthreads();
        if (tid < 128) fs[tid] += v;
        __syncthreads();
    }
    if (tid < 128) {
        int ex = fs[tid] - fh[tid];  // exclusive base within bucket
        rb[tid] = ex;
        int node = (b << 7) + tid;
        if (node < N) off[node] = cb0 + ex;
    }
    if (b == C - 1 && tid == 0) off[N] = E;
    __syncthreads();
    for (int p = cb0 + tid; p < cb1; p += 256) {
        int t = tgtc[p];
        int r = atomicAdd(&rb[t & 127], 1);
        int fpos = cb0 + r;
        int e = ec[p];
        eidx[fpos] = e;
        srcp[fpos] = src[e];
    }
}

// batch is sorted: mark graph boundaries directly
__global__ void gbound_kernel(const int* __restrict__ batch, int* __restrict__ goff,
                              int N, int G) {
    int i = blockIdx.x * 256 + threadIdx.x;
    if (i >= N) return;
    int b = batch[i];
    if (i == 0) {
        for (int g = 0; g <= b; ++g) goff[g] = 0;
    } else {
        int bp = batch[i - 1];
        for (int g = bp + 1; g <= b; ++g) goff[g] = i;
    }
    if (i == N - 1) {
        for (int g = b + 1; g <= G; ++g) goff[g] = N;
    }
}

// ---------------------------------------------------------------------------
// Permute+convert edge_attr to bf16 in target-sorted order (coalesced writes)
// ---------------------------------------------------------------------------
__global__ __launch_bounds__(256) void perm_ea_kernel(
    const float* __restrict__ ea, const int* __restrict__ eidx,
    unsigned short* __restrict__ out, int E) {
    int p = blockIdx.x * 256 + threadIdx.x;
    if (p >= E) return;
    int e = eidx[p];
    const float4* r = (const float4*)(ea + (size_t)e * EDGE_DIM);
    union { unsigned short us[EDGE_DIM]; uint4 u4[EDGE_DIM / 8]; } tmp;
#pragma unroll
    for (int q = 0; q < EDGE_DIM / 4; ++q) {
        float4 v = r[q];
        tmp.us[4 * q]     = f2bf(v.x);
        tmp.us[4 * q + 1] = f2bf(v.y);
        tmp.us[4 * q + 2] = f2bf(v.z);
        tmp.us[4 * q + 3] = f2bf(v.w);
    }
    uint4* o = (uint4*)(out + (size_t)p * EDGE_DIM);
#pragma unroll
    for (int k = 0; k < EDGE_DIM / 8; ++k) o[k] = tmp.u4[k];
}

// ---------------------------------------------------------------------------
// Parallel weight swizzle into MFMA A-frag order: one block per 16x32 tile.
// 56 tiles/layer: [0,8) fW1, [8,24) fW2, [24,40) oW1, [40,56) oW2.
// ---------------------------------------------------------------------------
__global__ void swizzle_w_kernel(const float* __restrict__ fW1, const float* __restrict__ fW2,
                                 const float* __restrict__ oW1, const float* __restrict__ oW2,
                                 unsigned short* __restrict__ W1sw, unsigned short* __restrict__ W2sw,
                                 unsigned short* __restrict__ oW1sw, unsigned short* __restrict__ oW2sw) {
    int i = blockIdx.x / 56, r = blockIdx.x % 56;
    int L = threadIdx.x;
    int e = L & 15, q = L >> 4;
    const float* W;
    unsigned short* out;
    int K, M, t;
    if (r < 8)       { W = fW1 + (size_t)i * EDGE_DIM * HIDDEN;  out = W1sw  + (size_t)i * 8 * 512;  K = EDGE_DIM; M = HIDDEN;   t = r; }
    else if (r < 24) { W = fW2 + (size_t)i * HIDDEN * NODE_DIM;  out = W2sw  + (size_t)i * 16 * 512; K = HIDDEN;   M = NODE_DIM; t = r - 8; }
    else if (r < 40) { W = oW1 + (size_t)i * NODE_DIM * HIDDEN;  out = oW1sw + (size_t)i * 16 * 512; K = NODE_DIM; M = HIDDEN;   t = r - 24; }
    else             { W = oW2 + (size_t)i * HIDDEN * NODE_DIM;  out = oW2sw + (size_t)i * 16 * 512; K = HIDDEN;   M = NODE_DIM; t = r - 40; }
    int nc = K >> 5;
    int mt = t / nc, s = t - mt * nc;
    union { unsigned short us[8]; uint4 u4; } pk;
#pragma unroll
    for (int j = 0; j < 8; ++j)
        pk.us[j] = f2bf(W[(size_t)(32 * s + 8 * q + j) * M + 16 * mt + e]);
    *(uint4*)(out + ((size_t)t * 64 + L) * 8) = pk.u4;
}

#define HSTRIDE 136  // shorts; 128 + 8 pad, keeps 16B alignment for ds_read_b128

// ---------------------------------------------------------------------------
// Per-16-edge-group pipeline: MFMA1 interleaved with tanh (sub-rounds of 4
// tiles -> peak 16 acc regs), early hd gather, MFMA2 split into nt-pairs
// (peak 8 acc regs). Register-lean but NOT occupancy-forced (r4 lesson:
// __launch_bounds__(256,5) caused scratch spills, 8x write amplification).
// ---------------------------------------------------------------------------
__device__ __forceinline__ void eg_process(
    bf16x8 eaf, int sidx, int pdst, bool valid,
    unsigned short* hrow, int lane, int q,
    const unsigned short* __restrict__ W1sw, const float* __restrict__ b1,
    const unsigned short* __restrict__ W2sw, const float* __restrict__ b2,
    const float* __restrict__ av, const float* __restrict__ hd,
    unsigned short* __restrict__ msg, float* __restrict__ score) {
    // ---- phase 1: hidden = tanh(ea @ W1 + b1), staged bf16 in LDS ----
#pragma unroll
    for (int th = 0; th < 2; ++th) {
        f32x4 c[4];
#pragma unroll
        for (int t = 0; t < 4; ++t) {
            bf16x8 a = *(const bf16x8*)(W1sw + ((th * 4 + t) * 64 + lane) * 8);
            c[t] = __builtin_amdgcn_mfma_f32_16x16x32_bf16(a, eaf, (f32x4){0.f, 0.f, 0.f, 0.f}, 0, 0, 0);
        }
#pragma unroll
        for (int t = 0; t < 4; ++t) {
            int tt = th * 4 + t;
            float4 b = *(const float4*)(b1 + 16 * tt + 4 * q);
            unsigned h0 = f2bf(fast_tanh(c[t][0] + b.x));
            unsigned h1 = f2bf(fast_tanh(c[t][1] + b.y));
            unsigned h2 = f2bf(fast_tanh(c[t][2] + b.z));
            unsigned h3 = f2bf(fast_tanh(c[t][3] + b.w));
            uint2 pk;
            pk.x = h0 | (h1 << 16);
            pk.y = h2 | (h3 << 16);
            *(uint2*)(hrow + 16 * tt + 4 * q) = pk;  // ds_write_b64
        }
    }

    // ---- early gather: hd[src] in flight while MFMA2 runs ----
    float4 hv[4];
#pragma unroll
    for (int nt = 0; nt < 4; ++nt)
        hv[nt] = *(const float4*)(hd + (size_t)sidx * NODE_DIM + 16 * nt + 4 * q);

    // ---- phase 2: ew = hidden @ W2, nt-pairs; tail fused per pair ----
    float sc = 0.f;
#pragma unroll
    for (int np = 0; np < 2; ++np) {
        f32x4 c2[2] = {{0.f, 0.f, 0.f, 0.f}, {0.f, 0.f, 0.f, 0.f}};
#pragma unroll
        for (int s = 0; s < 4; ++s) {
            bf16x8 hf = *(const bf16x8*)(hrow + 32 * s + 8 * q);
            bf16x8 a0 = *(const bf16x8*)(W2sw + (((2 * np + 0) * 4 + s) * 64 + lane) * 8);
            bf16x8 a1 = *(const bf16x8*)(W2sw + (((2 * np + 1) * 4 + s) * 64 + lane) * 8);
            c2[0] = __builtin_amdgcn_mfma_f32_16x16x32_bf16(a0, hf, c2[0], 0, 0, 0);
            c2[1] = __builtin_amdgcn_mfma_f32_16x16x32_bf16(a1, hf, c2[1], 0, 0, 0);
        }
#pragma unroll
        for (int k = 0; k < 2; ++k) {
            int nt = 2 * np + k;
            float4 bb = *(const float4*)(b2 + 16 * nt + 4 * q);
            float4 vv = *(const float4*)(av + 16 * nt + 4 * q);
            float4 hh = hv[nt];
            float m0 = (c2[k][0] + bb.x) * hh.x;
            float m1 = (c2[k][1] + bb.y) * hh.y;
            float m2 = (c2[k][2] + bb.z) * hh.z;
            float m3 = (c2[k][3] + bb.w) * hh.w;
            uint2 pk;
            pk.x = (unsigned)f2bf(m0) | ((unsigned)f2bf(m1) << 16);
            pk.y = (unsigned)f2bf(m2) | ((unsigned)f2bf(m3) << 16);
            if (valid) *(uint2*)(msg + (size_t)pdst * NODE_DIM + 16 * nt + 4 * q) = pk;
            sc += m0 * vv.x + m1 * vv.y + m2 * vv.z + m3 * vv.w;
        }
    }
    sc += __shfl_xor(sc, 16, 64);
    sc += __shfl_xor(sc, 32, 64);
    if (q == 0 && valid) score[pdst] = sc;
}

// ---------------------------------------------------------------------------
// MFMA edge kernel: wave per 32 edges, two sequential 16-edge groups sharing
// one LDS H buffer (17.4 KB/block). No min-waves bound (avoids spills).
// ---------------------------------------------------------------------------
__global__ __launch_bounds__(256) void edge_mfma_kernel(
    const unsigned short* __restrict__ ea_p, const float* __restrict__ hd,
    const unsigned short* __restrict__ W1sw, const float* __restrict__ b1,
    const unsigned short* __restrict__ W2sw, const float* __restrict__ b2,
    const float* __restrict__ av, const int* __restrict__ srcp,
    unsigned short* __restrict__ msg, float* __restrict__ score, int E) {
    __shared__ unsigned short Hl[4][16 * HSTRIDE];
    int wave = threadIdx.x >> 6, lane = threadIdx.x & 63;
    int e = lane & 15, q = lane >> 4;
    int p0 = blockIdx.x * 128 + wave * 32;
    if (p0 >= E) return;
    int pA = p0 + e, pB = p0 + 16 + e;
    int pAc = pA < E ? pA : E - 1;
    int pBc = pB < E ? pB : E - 1;
    bool vA = pA < E, vB = pB < E;

    bf16x8 eafA = *(const bf16x8*)(ea_p + (size_t)pAc * EDGE_DIM + q * 8);
    bf16x8 eafB = *(const bf16x8*)(ea_p + (size_t)pBc * EDGE_DIM + q * 8);
    int sA = srcp[pAc];
    int sB = srcp[pBc];
    unsigned short* hrow = &Hl[wave][e * HSTRIDE];

    eg_process(eafA, sA, pA, vA, hrow, lane, q, W1sw, b1, W2sw, b2, av, hd, msg, score);
    eg_process(eafB, sB, pB, vB, hrow, lane, q, W1sw, b1, W2sw, b2, av, hd, msg, score);
}

// ---------------------------------------------------------------------------
// Fused node out-MLP (MFMA): delta = tanh(agg@oW1+b1)@oW2+b2; h += delta
// ---------------------------------------------------------------------------
__global__ __launch_bounds__(256) void node_mlp_kernel(
    const float* __restrict__ agg,
    const unsigned short* __restrict__ W1sw, const float* __restrict__ b1,
    const unsigned short* __restrict__ W2sw, const float* __restrict__ b2,
    float* __restrict__ h, int N) {
    __shared__ unsigned short Hl[4][16 * HSTRIDE];
    int wave = threadIdx.x >> 6, lane = threadIdx.x & 63;
    int e = lane & 15, q = lane >> 4;
    int n0 = (blockIdx.x * 4 + wave) * 16;
    if (n0 >= N) return;
    int ne = n0 + e;
    int neC = ne < N ? ne : N - 1;
    bool ok = ne < N;

    bf16x8 bfr[2];
#pragma unroll
    for (int s = 0; s < 2; ++s) {
        const float4* ar = (const float4*)(agg + (size_t)neC * NODE_DIM + 32 * s + 8 * q);
        float4 x0 = ar[0], x1 = ar[1];
        union { bf16x8 v; unsigned short us[8]; } u;
        u.us[0] = f2bf(x0.x); u.us[1] = f2bf(x0.y);
        u.us[2] = f2bf(x0.z); u.us[3] = f2bf(x0.w);
        u.us[4] = f2bf(x1.x); u.us[5] = f2bf(x1.y);
        u.us[6] = f2bf(x1.z); u.us[7] = f2bf(x1.w);
        bfr[s] = u.v;
    }

    f32x4 c1[8];
#pragma unroll
    for (int t = 0; t < 8; ++t) {
        bf16x8 a0 = *(const bf16x8*)(W1sw + ((t * 2 + 0) * 64 + lane) * 8);
        bf16x8 a1 = *(const bf16x8*)(W1sw + ((t * 2 + 1) * 64 + lane) * 8);
        c1[t] = __builtin_amdgcn_mfma_f32_16x16x32_bf16(a0, bfr[0], (f32x4){0.f, 0.f, 0.f, 0.f}, 0, 0, 0);
        c1[t] = __builtin_amdgcn_mfma_f32_16x16x32_bf16(a1, bfr[1], c1[t], 0, 0, 0);
    }

    unsigned short* hrow = &Hl[wave][e * HSTRIDE];
#pragma unroll
    for (int t = 0; t < 8; ++t) {
        float4 b = *(const float4*)(b1 + 16 * t + 4 * q);
        unsigned h0 = f2bf(fast_tanh(c1[t][0] + b.x));
        unsigned h1 = f2bf(fast_tanh(c1[t][1] + b.y));
        unsigned h2 = f2bf(fast_tanh(c1[t][2] + b.z));
        unsigned h3 = f2bf(fast_tanh(c1[t][3] + b.w));
        uint2 pk;
        pk.x = h0 | (h1 << 16);
        pk.y = h2 | (h3 << 16);
        *(uint2*)(hrow + 16 * t + 4 * q) = pk;
    }

    f32x4 c2[4] = {{0.f, 0.f, 0.f, 0.f}, {0.f, 0.f, 0.f, 0.f},
                   {0.f, 0.f, 0.f, 0.f}, {0.f, 0.f, 0.f, 0.f}};
#pragma unroll
    for (int s = 0; s < 4; ++s) {
        bf16x8 hf = *(const bf16x8*)(hrow + 32 * s + 8 * q);
#pragma unroll
        for (int nt = 0; nt < 4; ++nt) {
            bf16x8 a = *(const bf16x8*)(W2sw + ((nt * 4 + s) * 64 + lane) * 8);
            c2[nt] = __builtin_amdgcn_mfma_f32_16x16x32_bf16(a, hf, c2[nt], 0, 0, 0);
        }
    }

    if (ok) {
#pragma unroll
        for (int nt = 0; nt < 4; ++nt) {
            float4 bb = *(const float4*)(b2 + 16 * nt + 4 * q);
            float4* hp = (float4*)(h + (size_t)ne * NODE_DIM + 16 * nt + 4 * q);
            float4 hv = *hp;
            hv.x += c2[nt][0] + bb.x;
            hv.y += c2[nt][1] + bb.y;
            hv.z += c2[nt][2] + bb.z;
            hv.w += c2[nt][3] + bb.w;
            *hp = hv;
        }
    }
}

// ---------------------------------------------------------------------------
// Generic dense layer (fp32): hd and final output MLP
// ---------------------------------------------------------------------------
template <int K, int M, bool ACT, bool RESID>
__global__ __launch_bounds__(256) void dense_kernel(
    const float* __restrict__ X, const float* __restrict__ W,
    const float* __restrict__ bias, float* __restrict__ Y, int rows) {
    int tid = blockIdx.x * 256 + threadIdx.x;
    int row = tid / M;
    int d = tid - row * M;
    if (row >= rows) return;
    if (M >= 64) row = __builtin_amdgcn_readfirstlane(row);
    const float* __restrict__ x = X + (size_t)row * K;
    float acc = bias ? bias[d] : 0.f;
#pragma unroll
    for (int k = 0; k < K; ++k) acc += x[k] * W[k * M + d];
    if (ACT) acc = fast_tanh(acc);
    if (RESID) acc += Y[(size_t)row * M + d];
    Y[(size_t)row * M + d] = acc;
}

// ---------------------------------------------------------------------------
// Aggregation: wave per node; single streaming pass (no-max softmax, no gather)
// ---------------------------------------------------------------------------
__global__ __launch_bounds__(256) void agg_kernel(
    const unsigned short* __restrict__ msg, const float* __restrict__ score,
    const int* __restrict__ off, float* __restrict__ agg, int n) {
    int tid = blockIdx.x * 256 + threadIdx.x;
    int wid = tid >> 6;
    int lane = threadIdx.x & 63;
    if (wid >= n) return;
    wid = __builtin_amdgcn_readfirstlane(wid);
    int o0 = off[wid], o1 = off[wid + 1];
    int g = lane >> 3, s = lane & 7;
    if (o1 <= o0) {
        if (g == 0) {
            float4 z = {0.f, 0.f, 0.f, 0.f};
            float4* dst = (float4*)(agg + (size_t)wid * NODE_DIM + s * 8);
            dst[0] = z; dst[1] = z;
        }
        return;
    }
    float den = 0.f;
    float acc[8] = {0.f, 0.f, 0.f, 0.f, 0.f, 0.f, 0.f, 0.f};
    for (int p = o0; p < o1; p += 8) {
        int pe = p + g;
        int pc = (pe < o1) ? pe : (o1 - 1);
        float w = (pe < o1) ? __expf(fminf(score[pc], 60.f)) : 0.f;
        den += w;
        union { bf16x8 v; unsigned short us[8]; } eu;
        eu.v = *(const bf16x8*)(msg + (size_t)pc * NODE_DIM + s * 8);
        acc[0] += w * bf2f(eu.us[0]);
        acc[1] += w * bf2f(eu.us[1]);
        acc[2] += w * bf2f(eu.us[2]);
        acc[3] += w * bf2f(eu.us[3]);
        acc[4] += w * bf2f(eu.us[4]);
        acc[5] += w * bf2f(eu.us[5]);
        acc[6] += w * bf2f(eu.us[6]);
        acc[7] += w * bf2f(eu.us[7]);
    }
    // reduce across the 8 g-groups (lanes within a g-group hold identical den)
#pragma unroll
    for (int j = 0; j < 8; ++j) {
        acc[j] += __shfl_xor(acc[j], 8, 64);
        acc[j] += __shfl_xor(acc[j], 16, 64);
        acc[j] += __shfl_xor(acc[j], 32, 64);
    }
    den += __shfl_xor(den, 8, 64);
    den += __shfl_xor(den, 16, 64);
    den += __shfl_xor(den, 32, 64);
    if (g == 0) {
        float inv = __builtin_amdgcn_rcpf(den);
        inv = inv * (2.f - den * inv);
        float4 r0 = {acc[0] * inv, acc[1] * inv, acc[2] * inv, acc[3] * inv};
        float4 r1 = {acc[4] * inv, acc[5] * inv, acc[6] * inv, acc[7] * inv};
        float4* dst = (float4*)(agg + (size_t)wid * NODE_DIM + s * 8);
        dst[0] = r0; dst[1] = r1;
    }
}

// ---------------------------------------------------------------------------
// Mean pool per graph: 4 waves per graph + LDS reduce
// ---------------------------------------------------------------------------
__global__ __launch_bounds__(256) void pool_kernel(const float* __restrict__ h,
                                                   const int* __restrict__ goff,
                                                   float* __restrict__ pooled) {
    __shared__ float sh[4][NODE_DIM];
    int g = blockIdx.x;
    int w = threadIdx.x >> 6, d = threadIdx.x & 63;
    int o0 = goff[g], o1 = goff[g + 1];
    float acc = 0.f;
    for (int n = o0 + w; n < o1; n += 4) acc += h[(size_t)n * NODE_DIM + d];
    sh[w][d] = acc;
    __syncthreads();
    if (w == 0) {
        float sum = sh[0][d] + sh[1][d] + sh[2][d] + sh[3][d];
        int c = o1 - o0;
        if (c < 1) c = 1;
        pooled[g * NODE_DIM + d] = sum / (float)c;
    }
}

// ---------------------------------------------------------------------------
extern "C" void kernel_launch(void* const* d_in, const int* in_sizes, int n_in,
                              void* d_out, int out_size, void* d_ws, size_t ws_size,
                              hipStream_t stream) {
    const float* x         = (const float*)d_in[0];
    const float* edge_attr = (const float*)d_in[1];
    const int*   ei        = (const int*)d_in[2];
    const int*   batch     = (const int*)d_in[3];
    const float* Wd        = (const float*)d_in[4];
    const float* fW1       = (const float*)d_in[5];
    const float* fb1       = (const float*)d_in[6];
    const float* fW2       = (const float*)d_in[7];
    const float* fb2       = (const float*)d_in[8];
    const float* av        = (const float*)d_in[9];
    const float* oW1       = (const float*)d_in[10];
    const float* ob1       = (const float*)d_in[11];
    const float* oW2       = (const float*)d_in[12];
    const float* ob2       = (const float*)d_in[13];
    const float* nW1       = (const float*)d_in[14];
    const float* nb1       = (const float*)d_in[15];
    const float* nW2       = (const float*)d_in[16];
    const float* nb2       = (const float*)d_in[17];
    float* out = (float*)d_out;

    const int N = in_sizes[0] / NODE_DIM;   // 50000
    const int E = in_sizes[2] / 2;          // 800000
    const int G = NGRAPH;
    const int NB = (E + 4095) / 4096;       // coarse blocks (196)
    const int C  = (N + 127) >> 7;          // coarse buckets (391)
    const int SN = C * NB;                  // scan length (76636)
    const int SB = (SN + 255) / 256;        // scan blocks (300, must be <=1024)

    char* base = (char*)d_ws;
    size_t pos = 0;
    auto alloc = [&](size_t bytes) -> void* {
        pos = (pos + 255) & ~(size_t)255;
        void* r = base + pos;
        pos += bytes;
        return r;
    };
    int* Hc   = (int*)alloc((size_t)SN * 4);
    int* Sc   = (int*)alloc(((size_t)SN + 1) * 4);
    int* bsum = (int*)alloc((size_t)1024 * 4);
    int* tgtc = (int*)alloc((size_t)E * 4);
    int* ec   = (int*)alloc((size_t)E * 4);
    int* off  = (int*)alloc((size_t)(N + 1) * 4);
    int* goff = (int*)alloc((size_t)(G + 1) * 4);
    int* eidx = (int*)alloc((size_t)E * 4);
    int* srcp = (int*)alloc((size_t)E * 4);
    float* score = (float*)alloc((size_t)E * 4);
    float* hd    = (float*)alloc((size_t)N * NODE_DIM * 4);
    float* h     = (float*)alloc((size_t)N * NODE_DIM * 4);
    float* agg   = (float*)alloc((size_t)N * NODE_DIM * 4);
    float* pooled = (float*)alloc((size_t)G * NODE_DIM * 4);
    float* t2     = (float*)alloc((size_t)G * HIDDEN * 4);
    unsigned short* ea_p  = (unsigned short*)alloc((size_t)E * EDGE_DIM * 2);
    unsigned short* msg   = (unsigned short*)alloc((size_t)E * NODE_DIM * 2);
    unsigned short* W1sw  = (unsigned short*)alloc((size_t)N_LAYERS * 8 * 512 * 2);
    unsigned short* W2sw  = (unsigned short*)alloc((size_t)N_LAYERS * 16 * 512 * 2);
    unsigned short* oW1sw = (unsigned short*)alloc((size_t)N_LAYERS * 16 * 512 * 2);
    unsigned short* oW2sw = (unsigned short*)alloc((size_t)N_LAYERS * 16 * 512 * 2);
    (void)ws_size;

    const int* src = ei;
    const int* tgt = ei + E;

    // --- prep: two-level counting sort, hierarchical scan (no global atomics) ---
    coarse_hist_kernel<<<NB, 256, 0, stream>>>(tgt, Hc, E, C, NB);
    scan1_kernel<<<SB, 256, 0, stream>>>(Hc, Sc, bsum, SN);
    scan2_kernel<<<1, 1024, 0, stream>>>(bsum, SB);
    scan3_kernel<<<SB, 256, 0, stream>>>(Sc, bsum, SN);
    coarse_scatter_kernel<<<NB, 256, 0, stream>>>(tgt, Sc, tgtc, ec, E, C, NB);
    fine_sort_kernel<<<C, 256, 0, stream>>>(Sc, tgtc, ec, src, off, eidx, srcp, E, N, C, NB);
    gbound_kernel<<<(N + 255) / 256, 256, 0, stream>>>(batch, goff, N, G);
    perm_ea_kernel<<<(E + 255) / 256, 256, 0, stream>>>(edge_attr, eidx, ea_p, E);
    swizzle_w_kernel<<<N_LAYERS * 56, 64, 0, stream>>>(fW1, fW2, oW1, oW2, W1sw, W2sw, oW1sw, oW2sw);
    hipMemcpyAsync(h, x, (size_t)N * NODE_DIM * 4, hipMemcpyDeviceToDevice, stream);

    const int node_tiles = (N + 15) / 16;
    for (int i = 0; i < N_LAYERS; ++i) {
        dense_kernel<NODE_DIM, NODE_DIM, false, false>
            <<<(N * NODE_DIM + 255) / 256, 256, 0, stream>>>(
                h, Wd + (size_t)i * NODE_DIM * NODE_DIM, nullptr, hd, N);
        edge_mfma_kernel<<<(E + 127) / 128, 256, 0, stream>>>(
            ea_p, hd,
            W1sw + (size_t)i * 8 * 512, fb1 + (size_t)i * HIDDEN,
            W2sw + (size_t)i * 16 * 512, fb2 + (size_t)i * NODE_DIM,
            av + (size_t)i * NODE_DIM, srcp, msg, score, E);
        agg_kernel<<<(N + 3) / 4, 256, 0, stream>>>(msg, score, off, agg, N);
        node_mlp_kernel<<<(node_tiles + 3) / 4, 256, 0, stream>>>(
            agg,
            oW1sw + (size_t)i * 16 * 512, ob1 + (size_t)i * HIDDEN,
            oW2sw + (size_t)i * 16 * 512, ob2 + (size_t)i * NODE_DIM,
            h, N);
    }

    pool_kernel<<<G, 256, 0, stream>>>(h, goff, pooled);
    dense_kernel<NODE_DIM, HIDDEN, true, false>
        <<<(G * HIDDEN + 255) / 256, 256, 0, stream>>>(pooled, nW1, nb1, t2, G);
    dense_kernel<HIDDEN, OUT_DIM, false, false>
        <<<(G * OUT_DIM + 255) / 256, 256, 0, stream>>>(t2, nW2, nb2, out, G);
}

// Round 6
// 717.535 us; speedup vs baseline: 2.1101x; 1.0824x over previous
//
#include <hip/hip_runtime.h>
#include <hip/hip_bf16.h>
#include <math.h>

#define NODE_DIM 64
#define EDGE_DIM 32
#define HIDDEN   128
#define OUT_DIM  32
#define N_LAYERS 3
#define NGRAPH   128

typedef __attribute__((ext_vector_type(8))) short bf16x8;
typedef __attribute__((ext_vector_type(4))) float f32x4;

__device__ __forceinline__ unsigned short f2bf(float f) {
    unsigned u = __float_as_uint(f);
    u = (u + 0x7fffu + ((u >> 16) & 1u)) >> 16;
    return (unsigned short)u;
}
__device__ __forceinline__ float bf2f(unsigned short h) {
    return __uint_as_float((unsigned)h << 16);
}
// tanh(x) = 2/(1+exp(-2x)) - 1 : saturates correctly at +/-1, no abs/copysign
__device__ __forceinline__ float fast_tanh(float x) {
    float e = __expf(-2.f * x);
    float r = __builtin_amdgcn_rcpf(1.f + e);
    return __builtin_fmaf(2.f, r, -1.f);
}

// ---------------------------------------------------------------------------
// Two-level counting sort of edges by target node — LDS atomics only.
// Coarse bucket = tgt >> 7 (128 nodes per bucket). EPB = 4096 edges/block.
// ---------------------------------------------------------------------------
__global__ __launch_bounds__(256) void coarse_hist_kernel(
    const int* __restrict__ tgt, int* __restrict__ Hc, int E, int C, int NB) {
    __shared__ int lh[512];
    int blk = blockIdx.x, tid = threadIdx.x;
    for (int b = tid; b < C; b += 256) lh[b] = 0;
    __syncthreads();
    int base = blk * 4096;
#pragma unroll
    for (int i = 0; i < 16; ++i) {
        int e = base + i * 256 + tid;
        if (e < E) atomicAdd(&lh[tgt[e] >> 7], 1);
    }
    __syncthreads();
    for (int b = tid; b < C; b += 256) Hc[(size_t)b * NB + blk] = lh[b];
}

// ---------------------------------------------------------------------------
// Hierarchical exclusive scan (3 phases), n up to 256*1024 elements
// ---------------------------------------------------------------------------
__global__ __launch_bounds__(256) void scan1_kernel(const int* __restrict__ c,
                                                    int* __restrict__ o,
                                                    int* __restrict__ bsum, int n) {
    __shared__ int sh[256];
    int b = blockIdx.x, t = threadIdx.x;
    int i = b * 256 + t;
    int v = (i < n) ? c[i] : 0;
    sh[t] = v;
    __syncthreads();
    for (int d = 1; d < 256; d <<= 1) {
        int u = (t >= d) ? sh[t - d] : 0;
        __syncthreads();
        sh[t] += u;
        __syncthreads();
    }
    if (i < n) o[i] = sh[t] - v;          // exclusive within block
    if (t == 255) bsum[b] = sh[255];      // block total
}

__global__ void scan2_kernel(int* __restrict__ bsum, int nb) {
    __shared__ int sh[1024];
    int t = threadIdx.x;
    int v = (t < nb) ? bsum[t] : 0;
    sh[t] = v;
    __syncthreads();
    for (int d = 1; d < 1024; d <<= 1) {
        int u = (t >= d) ? sh[t - d] : 0;
        __syncthreads();
        sh[t] += u;
        __syncthreads();
    }
    if (t < nb) bsum[t] = sh[t] - v;      // exclusive block offsets
}

__global__ __launch_bounds__(256) void scan3_kernel(int* __restrict__ o,
                                                    const int* __restrict__ bsum, int n) {
    int i = blockIdx.x * 256 + threadIdx.x;
    if (i < n) o[i] += bsum[blockIdx.x];
}

__global__ __launch_bounds__(256) void coarse_scatter_kernel(
    const int* __restrict__ tgt, const int* __restrict__ Sc,
    int* __restrict__ tgtc, int* __restrict__ ec, int E, int C, int NB) {
    __shared__ int lb[512];
    int blk = blockIdx.x, tid = threadIdx.x;
    for (int b = tid; b < C; b += 256) lb[b] = Sc[(size_t)b * NB + blk];
    __syncthreads();
    int base = blk * 4096;
#pragma unroll
    for (int i = 0; i < 16; ++i) {
        int e = base + i * 256 + tid;
        if (e < E) {
            int t = tgt[e];
            int pos = atomicAdd(&lb[t >> 7], 1);
            tgtc[pos] = t;
            ec[pos] = e;
        }
    }
}

// One block per coarse bucket: fine 128-bin sort + off[] emission.
__global__ __launch_bounds__(256) void fine_sort_kernel(
    const int* __restrict__ Sc, const int* __restrict__ tgtc,
    const int* __restrict__ ec, const int* __restrict__ src,
    int* __restrict__ off, int* __restrict__ eidx, int* __restrict__ srcp,
    int E, int N, int C, int NB) {
    __shared__ int fh[128], fs[128], rb[128];
    int b = blockIdx.x, tid = threadIdx.x;
    int cb0 = Sc[(size_t)b * NB];
    int cb1 = (b + 1 < C) ? Sc[(size_t)(b + 1) * NB] : E;
    if (tid < 128) fh[tid] = 0;
    __syncthreads();
    for (int p = cb0 + tid; p < cb1; p += 256) atomicAdd(&fh[tgtc[p] & 127], 1);
    __syncthreads();
    if (tid < 128) fs[tid] = fh[tid];
    __syncthreads();
    for (int d = 1; d < 128; d <<= 1) {
        int v = 0;
        if (tid < 128 && tid >= d) v = fs[tid - d];
        __syncthreads();
        if (tid < 128) fs[tid] += v;
        __syncthreads();
    }
    if (tid < 128) {
        int ex = fs[tid] - fh[tid];  // exclusive base within bucket
        rb[tid] = ex;
        int node = (b << 7) + tid;
        if (node < N) off[node] = cb0 + ex;
    }
    if (b == C - 1 && tid == 0) off[N] = E;
    __syncthreads();
    for (int p = cb0 + tid; p < cb1; p += 256) {
        int t = tgtc[p];
        int r = atomicAdd(&rb[t & 127], 1);
        int fpos = cb0 + r;
        int e = ec[p];
        eidx[fpos] = e;
        srcp[fpos] = src[e];
    }
}

// batch is sorted: mark graph boundaries directly
__global__ void gbound_kernel(const int* __restrict__ batch, int* __restrict__ goff,
                              int N, int G) {
    int i = blockIdx.x * 256 + threadIdx.x;
    if (i >= N) return;
    int b = batch[i];
    if (i == 0) {
        for (int g = 0; g <= b; ++g) goff[g] = 0;
    } else {
        int bp = batch[i - 1];
        for (int g = bp + 1; g <= b; ++g) goff[g] = i;
    }
    if (i == N - 1) {
        for (int g = b + 1; g <= G; ++g) goff[g] = N;
    }
}

// ---------------------------------------------------------------------------
// Permute+convert edge_attr to bf16 in target-sorted order (coalesced writes)
// ---------------------------------------------------------------------------
__global__ __launch_bounds__(256) void perm_ea_kernel(
    const float* __restrict__ ea, const int* __restrict__ eidx,
    unsigned short* __restrict__ out, int E) {
    int p = blockIdx.x * 256 + threadIdx.x;
    if (p >= E) return;
    int e = eidx[p];
    const float4* r = (const float4*)(ea + (size_t)e * EDGE_DIM);
    union { unsigned short us[EDGE_DIM]; uint4 u4[EDGE_DIM / 8]; } tmp;
#pragma unroll
    for (int q = 0; q < EDGE_DIM / 4; ++q) {
        float4 v = r[q];
        tmp.us[4 * q]     = f2bf(v.x);
        tmp.us[4 * q + 1] = f2bf(v.y);
        tmp.us[4 * q + 2] = f2bf(v.z);
        tmp.us[4 * q + 3] = f2bf(v.w);
    }
    uint4* o = (uint4*)(out + (size_t)p * EDGE_DIM);
#pragma unroll
    for (int k = 0; k < EDGE_DIM / 8; ++k) o[k] = tmp.u4[k];
}

// ---------------------------------------------------------------------------
// Parallel weight swizzle into MFMA A-frag order: one block per 16x32 tile.
// 56 tiles/layer: [0,8) fW1, [8,24) fW2, [24,40) oW1, [40,56) oW2.
// ---------------------------------------------------------------------------
__global__ void swizzle_w_kernel(const float* __restrict__ fW1, const float* __restrict__ fW2,
                                 const float* __restrict__ oW1, const float* __restrict__ oW2,
                                 unsigned short* __restrict__ W1sw, unsigned short* __restrict__ W2sw,
                                 unsigned short* __restrict__ oW1sw, unsigned short* __restrict__ oW2sw) {
    int i = blockIdx.x / 56, r = blockIdx.x % 56;
    int L = threadIdx.x;
    int e = L & 15, q = L >> 4;
    const float* W;
    unsigned short* out;
    int K, M, t;
    if (r < 8)       { W = fW1 + (size_t)i * EDGE_DIM * HIDDEN;  out = W1sw  + (size_t)i * 8 * 512;  K = EDGE_DIM; M = HIDDEN;   t = r; }
    else if (r < 24) { W = fW2 + (size_t)i * HIDDEN * NODE_DIM;  out = W2sw  + (size_t)i * 16 * 512; K = HIDDEN;   M = NODE_DIM; t = r - 8; }
    else if (r < 40) { W = oW1 + (size_t)i * NODE_DIM * HIDDEN;  out = oW1sw + (size_t)i * 16 * 512; K = NODE_DIM; M = HIDDEN;   t = r - 24; }
    else             { W = oW2 + (size_t)i * HIDDEN * NODE_DIM;  out = oW2sw + (size_t)i * 16 * 512; K = HIDDEN;   M = NODE_DIM; t = r - 40; }
    int nc = K >> 5;
    int mt = t / nc, s = t - mt * nc;
    union { unsigned short us[8]; uint4 u4; } pk;
#pragma unroll
    for (int j = 0; j < 8; ++j)
        pk.us[j] = f2bf(W[(size_t)(32 * s + 8 * q + j) * M + 16 * mt + e]);
    *(uint4*)(out + ((size_t)t * 64 + L) * 8) = pk.u4;
}

#define HSTRIDE 136  // shorts; 128 + 8 pad, keeps 16B alignment for ds_read_b128

// ---------------------------------------------------------------------------
// MFMA edge kernel: wave per 32 edges, two 16-edge groups A/B interleaved
// PER WEIGHT FRAGMENT (each frag loaded once, used twice immediately -> no
// hoisting of 24 frags; ILP=2 on every chain; peak acc 8-16 regs).
// Gentle cap (256,4): <=128 regs, ~50% occupancy, no spill headroom issues.
// ---------------------------------------------------------------------------
__global__ __launch_bounds__(256, 4) void edge_mfma_kernel(
    const unsigned short* __restrict__ ea_p, const float* __restrict__ hd,
    const unsigned short* __restrict__ W1sw, const float* __restrict__ b1,
    const unsigned short* __restrict__ W2sw, const float* __restrict__ b2,
    const float* __restrict__ av, const int* __restrict__ srcp,
    unsigned short* __restrict__ msg, float* __restrict__ score, int E) {
    __shared__ unsigned short Hl[4][2][16 * HSTRIDE];
    int wave = threadIdx.x >> 6, lane = threadIdx.x & 63;
    int e = lane & 15, q = lane >> 4;
    int p0 = blockIdx.x * 128 + wave * 32;
    if (p0 >= E) return;
    int pA = p0 + e, pB = p0 + 16 + e;
    int pAc = pA < E ? pA : E - 1;
    int pBc = pB < E ? pB : E - 1;
    bool vA = pA < E, vB = pB < E;

    bf16x8 eafA = *(const bf16x8*)(ea_p + (size_t)pAc * EDGE_DIM + q * 8);
    bf16x8 eafB = *(const bf16x8*)(ea_p + (size_t)pBc * EDGE_DIM + q * 8);
    int sA = srcp[pAc];
    int sB = srcp[pBc];
    unsigned short* hrA = &Hl[wave][0][e * HSTRIDE];
    unsigned short* hrB = &Hl[wave][1][e * HSTRIDE];

    // ---- phase 1: per-tile {load W1 frag, MFMA x2, tanh x2, LDS write x2} ----
#pragma unroll
    for (int t = 0; t < 8; ++t) {
        bf16x8 a = *(const bf16x8*)(W1sw + (t * 64 + lane) * 8);
        f32x4 cA = __builtin_amdgcn_mfma_f32_16x16x32_bf16(a, eafA, (f32x4){0.f, 0.f, 0.f, 0.f}, 0, 0, 0);
        f32x4 cB = __builtin_amdgcn_mfma_f32_16x16x32_bf16(a, eafB, (f32x4){0.f, 0.f, 0.f, 0.f}, 0, 0, 0);
        float4 b = *(const float4*)(b1 + 16 * t + 4 * q);
        {
            unsigned h0 = f2bf(fast_tanh(cA[0] + b.x));
            unsigned h1 = f2bf(fast_tanh(cA[1] + b.y));
            unsigned h2 = f2bf(fast_tanh(cA[2] + b.z));
            unsigned h3 = f2bf(fast_tanh(cA[3] + b.w));
            uint2 pk;
            pk.x = h0 | (h1 << 16);
            pk.y = h2 | (h3 << 16);
            *(uint2*)(hrA + 16 * t + 4 * q) = pk;  // ds_write_b64
        }
        {
            unsigned h0 = f2bf(fast_tanh(cB[0] + b.x));
            unsigned h1 = f2bf(fast_tanh(cB[1] + b.y));
            unsigned h2 = f2bf(fast_tanh(cB[2] + b.z));
            unsigned h3 = f2bf(fast_tanh(cB[3] + b.w));
            uint2 pk;
            pk.x = h0 | (h1 << 16);
            pk.y = h2 | (h3 << 16);
            *(uint2*)(hrB + 16 * t + 4 * q) = pk;
        }
    }

    // ---- phase 2: np-halves; hd gathers issued inside, used after 8 MFMAs ----
    float scA = 0.f, scB = 0.f;
#pragma unroll
    for (int np = 0; np < 2; ++np) {
        float4 hvA[2], hvB[2];
#pragma unroll
        for (int k = 0; k < 2; ++k) {
            hvA[k] = *(const float4*)(hd + (size_t)sA * NODE_DIM + 16 * (2 * np + k) + 4 * q);
            hvB[k] = *(const float4*)(hd + (size_t)sB * NODE_DIM + 16 * (2 * np + k) + 4 * q);
        }
        f32x4 c2A[2] = {{0.f, 0.f, 0.f, 0.f}, {0.f, 0.f, 0.f, 0.f}};
        f32x4 c2B[2] = {{0.f, 0.f, 0.f, 0.f}, {0.f, 0.f, 0.f, 0.f}};
#pragma unroll
        for (int s = 0; s < 4; ++s) {
            bf16x8 hfA = *(const bf16x8*)(hrA + 32 * s + 8 * q);
            bf16x8 hfB = *(const bf16x8*)(hrB + 32 * s + 8 * q);
            bf16x8 a0 = *(const bf16x8*)(W2sw + (((2 * np + 0) * 4 + s) * 64 + lane) * 8);
            bf16x8 a1 = *(const bf16x8*)(W2sw + (((2 * np + 1) * 4 + s) * 64 + lane) * 8);
            c2A[0] = __builtin_amdgcn_mfma_f32_16x16x32_bf16(a0, hfA, c2A[0], 0, 0, 0);
            c2B[0] = __builtin_amdgcn_mfma_f32_16x16x32_bf16(a0, hfB, c2B[0], 0, 0, 0);
            c2A[1] = __builtin_amdgcn_mfma_f32_16x16x32_bf16(a1, hfA, c2A[1], 0, 0, 0);
            c2B[1] = __builtin_amdgcn_mfma_f32_16x16x32_bf16(a1, hfB, c2B[1], 0, 0, 0);
        }
#pragma unroll
        for (int k = 0; k < 2; ++k) {
            int nt = 2 * np + k;
            float4 bb = *(const float4*)(b2 + 16 * nt + 4 * q);
            float4 vv = *(const float4*)(av + 16 * nt + 4 * q);
            {
                float4 hh = hvA[k];
                float m0 = (c2A[k][0] + bb.x) * hh.x;
                float m1 = (c2A[k][1] + bb.y) * hh.y;
                float m2 = (c2A[k][2] + bb.z) * hh.z;
                float m3 = (c2A[k][3] + bb.w) * hh.w;
                uint2 pk;
                pk.x = (unsigned)f2bf(m0) | ((unsigned)f2bf(m1) << 16);
                pk.y = (unsigned)f2bf(m2) | ((unsigned)f2bf(m3) << 16);
                if (vA) *(uint2*)(msg + (size_t)pA * NODE_DIM + 16 * nt + 4 * q) = pk;
                scA += m0 * vv.x + m1 * vv.y + m2 * vv.z + m3 * vv.w;
            }
            {
                float4 hh = hvB[k];
                float m0 = (c2B[k][0] + bb.x) * hh.x;
                float m1 = (c2B[k][1] + bb.y) * hh.y;
                float m2 = (c2B[k][2] + bb.z) * hh.z;
                float m3 = (c2B[k][3] + bb.w) * hh.w;
                uint2 pk;
                pk.x = (unsigned)f2bf(m0) | ((unsigned)f2bf(m1) << 16);
                pk.y = (unsigned)f2bf(m2) | ((unsigned)f2bf(m3) << 16);
                if (vB) *(uint2*)(msg + (size_t)pB * NODE_DIM + 16 * nt + 4 * q) = pk;
                scB += m0 * vv.x + m1 * vv.y + m2 * vv.z + m3 * vv.w;
            }
        }
    }
    scA += __shfl_xor(scA, 16, 64);
    scA += __shfl_xor(scA, 32, 64);
    scB += __shfl_xor(scB, 16, 64);
    scB += __shfl_xor(scB, 32, 64);
    if (q == 0) {
        if (vA) score[pA] = scA;
        if (vB) score[pB] = scB;
    }
}

// ---------------------------------------------------------------------------
// Fused node out-MLP (MFMA): delta = tanh(agg@oW1+b1)@oW2+b2; h += delta
// ---------------------------------------------------------------------------
__global__ __launch_bounds__(256) void node_mlp_kernel(
    const float* __restrict__ agg,
    const unsigned short* __restrict__ W1sw, const float* __restrict__ b1,
    const unsigned short* __restrict__ W2sw, const float* __restrict__ b2,
    float* __restrict__ h, int N) {
    __shared__ unsigned short Hl[4][16 * HSTRIDE];
    int wave = threadIdx.x >> 6, lane = threadIdx.x & 63;
    int e = lane & 15, q = lane >> 4;
    int n0 = (blockIdx.x * 4 + wave) * 16;
    if (n0 >= N) return;
    int ne = n0 + e;
    int neC = ne < N ? ne : N - 1;
    bool ok = ne < N;

    bf16x8 bfr[2];
#pragma unroll
    for (int s = 0; s < 2; ++s) {
        const float4* ar = (const float4*)(agg + (size_t)neC * NODE_DIM + 32 * s + 8 * q);
        float4 x0 = ar[0], x1 = ar[1];
        union { bf16x8 v; unsigned short us[8]; } u;
        u.us[0] = f2bf(x0.x); u.us[1] = f2bf(x0.y);
        u.us[2] = f2bf(x0.z); u.us[3] = f2bf(x0.w);
        u.us[4] = f2bf(x1.x); u.us[5] = f2bf(x1.y);
        u.us[6] = f2bf(x1.z); u.us[7] = f2bf(x1.w);
        bfr[s] = u.v;
    }

    f32x4 c1[8];
#pragma unroll
    for (int t = 0; t < 8; ++t) {
        bf16x8 a0 = *(const bf16x8*)(W1sw + ((t * 2 + 0) * 64 + lane) * 8);
        bf16x8 a1 = *(const bf16x8*)(W1sw + ((t * 2 + 1) * 64 + lane) * 8);
        c1[t] = __builtin_amdgcn_mfma_f32_16x16x32_bf16(a0, bfr[0], (f32x4){0.f, 0.f, 0.f, 0.f}, 0, 0, 0);
        c1[t] = __builtin_amdgcn_mfma_f32_16x16x32_bf16(a1, bfr[1], c1[t], 0, 0, 0);
    }

    unsigned short* hrow = &Hl[wave][e * HSTRIDE];
#pragma unroll
    for (int t = 0; t < 8; ++t) {
        float4 b = *(const float4*)(b1 + 16 * t + 4 * q);
        unsigned h0 = f2bf(fast_tanh(c1[t][0] + b.x));
        unsigned h1 = f2bf(fast_tanh(c1[t][1] + b.y));
        unsigned h2 = f2bf(fast_tanh(c1[t][2] + b.z));
        unsigned h3 = f2bf(fast_tanh(c1[t][3] + b.w));
        uint2 pk;
        pk.x = h0 | (h1 << 16);
        pk.y = h2 | (h3 << 16);
        *(uint2*)(hrow + 16 * t + 4 * q) = pk;
    }

    f32x4 c2[4] = {{0.f, 0.f, 0.f, 0.f}, {0.f, 0.f, 0.f, 0.f},
                   {0.f, 0.f, 0.f, 0.f}, {0.f, 0.f, 0.f, 0.f}};
#pragma unroll
    for (int s = 0; s < 4; ++s) {
        bf16x8 hf = *(const bf16x8*)(hrow + 32 * s + 8 * q);
#pragma unroll
        for (int nt = 0; nt < 4; ++nt) {
            bf16x8 a = *(const bf16x8*)(W2sw + ((nt * 4 + s) * 64 + lane) * 8);
            c2[nt] = __builtin_amdgcn_mfma_f32_16x16x32_bf16(a, hf, c2[nt], 0, 0, 0);
        }
    }

    if (ok) {
#pragma unroll
        for (int nt = 0; nt < 4; ++nt) {
            float4 bb = *(const float4*)(b2 + 16 * nt + 4 * q);
            float4* hp = (float4*)(h + (size_t)ne * NODE_DIM + 16 * nt + 4 * q);
            float4 hv = *hp;
            hv.x += c2[nt][0] + bb.x;
            hv.y += c2[nt][1] + bb.y;
            hv.z += c2[nt][2] + bb.z;
            hv.w += c2[nt][3] + bb.w;
            *hp = hv;
        }
    }
}

// ---------------------------------------------------------------------------
// Generic dense layer (fp32): hd and final output MLP
// ---------------------------------------------------------------------------
template <int K, int M, bool ACT, bool RESID>
__global__ __launch_bounds__(256) void dense_kernel(
    const float* __restrict__ X, const float* __restrict__ W,
    const float* __restrict__ bias, float* __restrict__ Y, int rows) {
    int tid = blockIdx.x * 256 + threadIdx.x;
    int row = tid / M;
    int d = tid - row * M;
    if (row >= rows) return;
    if (M >= 64) row = __builtin_amdgcn_readfirstlane(row);
    const float* __restrict__ x = X + (size_t)row * K;
    float acc = bias ? bias[d] : 0.f;
#pragma unroll
    for (int k = 0; k < K; ++k) acc += x[k] * W[k * M + d];
    if (ACT) acc = fast_tanh(acc);
    if (RESID) acc += Y[(size_t)row * M + d];
    Y[(size_t)row * M + d] = acc;
}

// ---------------------------------------------------------------------------
// Aggregation: wave per node; single streaming pass (no-max softmax, no gather)
// ---------------------------------------------------------------------------
__global__ __launch_bounds__(256) void agg_kernel(
    const unsigned short* __restrict__ msg, const float* __restrict__ score,
    const int* __restrict__ off, float* __restrict__ agg, int n) {
    int tid = blockIdx.x * 256 + threadIdx.x;
    int wid = tid >> 6;
    int lane = threadIdx.x & 63;
    if (wid >= n) return;
    wid = __builtin_amdgcn_readfirstlane(wid);
    int o0 = off[wid], o1 = off[wid + 1];
    int g = lane >> 3, s = lane & 7;
    if (o1 <= o0) {
        if (g == 0) {
            float4 z = {0.f, 0.f, 0.f, 0.f};
            float4* dst = (float4*)(agg + (size_t)wid * NODE_DIM + s * 8);
            dst[0] = z; dst[1] = z;
        }
        return;
    }
    float den = 0.f;
    float acc[8] = {0.f, 0.f, 0.f, 0.f, 0.f, 0.f, 0.f, 0.f};
    for (int p = o0; p < o1; p += 8) {
        int pe = p + g;
        int pc = (pe < o1) ? pe : (o1 - 1);
        float w = (pe < o1) ? __expf(fminf(score[pc], 60.f)) : 0.f;
        den += w;
        union { bf16x8 v; unsigned short us[8]; } eu;
        eu.v = *(const bf16x8*)(msg + (size_t)pc * NODE_DIM + s * 8);
        acc[0] += w * bf2f(eu.us[0]);
        acc[1] += w * bf2f(eu.us[1]);
        acc[2] += w * bf2f(eu.us[2]);
        acc[3] += w * bf2f(eu.us[3]);
        acc[4] += w * bf2f(eu.us[4]);
        acc[5] += w * bf2f(eu.us[5]);
        acc[6] += w * bf2f(eu.us[6]);
        acc[7] += w * bf2f(eu.us[7]);
    }
    // reduce across the 8 g-groups (lanes within a g-group hold identical den)
#pragma unroll
    for (int j = 0; j < 8; ++j) {
        acc[j] += __shfl_xor(acc[j], 8, 64);
        acc[j] += __shfl_xor(acc[j], 16, 64);
        acc[j] += __shfl_xor(acc[j], 32, 64);
    }
    den += __shfl_xor(den, 8, 64);
    den += __shfl_xor(den, 16, 64);
    den += __shfl_xor(den, 32, 64);
    if (g == 0) {
        float inv = __builtin_amdgcn_rcpf(den);
        inv = inv * (2.f - den * inv);
        float4 r0 = {acc[0] * inv, acc[1] * inv, acc[2] * inv, acc[3] * inv};
        float4 r1 = {acc[4] * inv, acc[5] * inv, acc[6] * inv, acc[7] * inv};
        float4* dst = (float4*)(agg + (size_t)wid * NODE_DIM + s * 8);
        dst[0] = r0; dst[1] = r1;
    }
}

// ---------------------------------------------------------------------------
// Mean pool per graph: 4 waves per graph + LDS reduce
// ---------------------------------------------------------------------------
__global__ __launch_bounds__(256) void pool_kernel(const float* __restrict__ h,
                                                   const int* __restrict__ goff,
                                                   float* __restrict__ pooled) {
    __shared__ float sh[4][NODE_DIM];
    int g = blockIdx.x;
    int w = threadIdx.x >> 6, d = threadIdx.x & 63;
    int o0 = goff[g], o1 = goff[g + 1];
    float acc = 0.f;
    for (int n = o0 + w; n < o1; n += 4) acc += h[(size_t)n * NODE_DIM + d];
    sh[w][d] = acc;
    __syncthreads();
    if (w == 0) {
        float sum = sh[0][d] + sh[1][d] + sh[2][d] + sh[3][d];
        int c = o1 - o0;
        if (c < 1) c = 1;
        pooled[g * NODE_DIM + d] = sum / (float)c;
    }
}

// ---------------------------------------------------------------------------
extern "C" void kernel_launch(void* const* d_in, const int* in_sizes, int n_in,
                              void* d_out, int out_size, void* d_ws, size_t ws_size,
                              hipStream_t stream) {
    const float* x         = (const float*)d_in[0];
    const float* edge_attr = (const float*)d_in[1];
    const int*   ei        = (const int*)d_in[2];
    const int*   batch     = (const int*)d_in[3];
    const float* Wd        = (const float*)d_in[4];
    const float* fW1       = (const float*)d_in[5];
    const float* fb1       = (const float*)d_in[6];
    const float* fW2       = (const float*)d_in[7];
    const float* fb2       = (const float*)d_in[8];
    const float* av        = (const float*)d_in[9];
    const float* oW1       = (const float*)d_in[10];
    const float* ob1       = (const float*)d_in[11];
    const float* oW2       = (const float*)d_in[12];
    const float* ob2       = (const float*)d_in[13];
    const float* nW1       = (const float*)d_in[14];
    const float* nb1       = (const float*)d_in[15];
    const float* nW2       = (const float*)d_in[16];
    const float* nb2       = (const float*)d_in[17];
    float* out = (float*)d_out;

    const int N = in_sizes[0] / NODE_DIM;   // 50000
    const int E = in_sizes[2] / 2;          // 800000
    const int G = NGRAPH;
    const int NB = (E + 4095) / 4096;       // coarse blocks (196)
    const int C  = (N + 127) >> 7;          // coarse buckets (391)
    const int SN = C * NB;                  // scan length (76636)
    const int SB = (SN + 255) / 256;        // scan blocks (300, must be <=1024)

    char* base = (char*)d_ws;
    size_t pos = 0;
    auto alloc = [&](size_t bytes) -> void* {
        pos = (pos + 255) & ~(size_t)255;
        void* r = base + pos;
        pos += bytes;
        return r;
    };
    int* Hc   = (int*)alloc((size_t)SN * 4);
    int* Sc   = (int*)alloc(((size_t)SN + 1) * 4);
    int* bsum = (int*)alloc((size_t)1024 * 4);
    int* tgtc = (int*)alloc((size_t)E * 4);
    int* ec   = (int*)alloc((size_t)E * 4);
    int* off  = (int*)alloc((size_t)(N + 1) * 4);
    int* goff = (int*)alloc((size_t)(G + 1) * 4);
    int* eidx = (int*)alloc((size_t)E * 4);
    int* srcp = (int*)alloc((size_t)E * 4);
    float* score = (float*)alloc((size_t)E * 4);
    float* hd    = (float*)alloc((size_t)N * NODE_DIM * 4);
    float* h     = (float*)alloc((size_t)N * NODE_DIM * 4);
    float* agg   = (float*)alloc((size_t)N * NODE_DIM * 4);
    float* pooled = (float*)alloc((size_t)G * NODE_DIM * 4);
    float* t2     = (float*)alloc((size_t)G * HIDDEN * 4);
    unsigned short* ea_p  = (unsigned short*)alloc((size_t)E * EDGE_DIM * 2);
    unsigned short* msg   = (unsigned short*)alloc((size_t)E * NODE_DIM * 2);
    unsigned short* W1sw  = (unsigned short*)alloc((size_t)N_LAYERS * 8 * 512 * 2);
    unsigned short* W2sw  = (unsigned short*)alloc((size_t)N_LAYERS * 16 * 512 * 2);
    unsigned short* oW1sw = (unsigned short*)alloc((size_t)N_LAYERS * 16 * 512 * 2);
    unsigned short* oW2sw = (unsigned short*)alloc((size_t)N_LAYERS * 16 * 512 * 2);
    (void)ws_size;

    const int* src = ei;
    const int* tgt = ei + E;

    // --- prep: two-level counting sort, hierarchical scan (no global atomics) ---
    coarse_hist_kernel<<<NB, 256, 0, stream>>>(tgt, Hc, E, C, NB);
    scan1_kernel<<<SB, 256, 0, stream>>>(Hc, Sc, bsum, SN);
    scan2_kernel<<<1, 1024, 0, stream>>>(bsum, SB);
    scan3_kernel<<<SB, 256, 0, stream>>>(Sc, bsum, SN);
    coarse_scatter_kernel<<<NB, 256, 0, stream>>>(tgt, Sc, tgtc, ec, E, C, NB);
    fine_sort_kernel<<<C, 256, 0, stream>>>(Sc, tgtc, ec, src, off, eidx, srcp, E, N, C, NB);
    gbound_kernel<<<(N + 255) / 256, 256, 0, stream>>>(batch, goff, N, G);
    perm_ea_kernel<<<(E + 255) / 256, 256, 0, stream>>>(edge_attr, eidx, ea_p, E);
    swizzle_w_kernel<<<N_LAYERS * 56, 64, 0, stream>>>(fW1, fW2, oW1, oW2, W1sw, W2sw, oW1sw, oW2sw);
    hipMemcpyAsync(h, x, (size_t)N * NODE_DIM * 4, hipMemcpyDeviceToDevice, stream);

    const int node_tiles = (N + 15) / 16;
    for (int i = 0; i < N_LAYERS; ++i) {
        dense_kernel<NODE_DIM, NODE_DIM, false, false>
            <<<(N * NODE_DIM + 255) / 256, 256, 0, stream>>>(
                h, Wd + (size_t)i * NODE_DIM * NODE_DIM, nullptr, hd, N);
        edge_mfma_kernel<<<(E + 127) / 128, 256, 0, stream>>>(
            ea_p, hd,
            W1sw + (size_t)i * 8 * 512, fb1 + (size_t)i * HIDDEN,
            W2sw + (size_t)i * 16 * 512, fb2 + (size_t)i * NODE_DIM,
            av + (size_t)i * NODE_DIM, srcp, msg, score, E);
        agg_kernel<<<(N + 3) / 4, 256, 0, stream>>>(msg, score, off, agg, N);
        node_mlp_kernel<<<(node_tiles + 3) / 4, 256, 0, stream>>>(
            agg,
            oW1sw + (size_t)i * 16 * 512, ob1 + (size_t)i * HIDDEN,
            oW2sw + (size_t)i * 16 * 512, ob2 + (size_t)i * NODE_DIM,
            h, N);
    }

    pool_kernel<<<G, 256, 0, stream>>>(h, goff, pooled);
    dense_kernel<NODE_DIM, HIDDEN, true, false>
        <<<(G * HIDDEN + 255) / 256, 256, 0, stream>>>(pooled, nW1, nb1, t2, G);
    dense_kernel<HIDDEN, OUT_DIM, false, false>
        <<<(G * OUT_DIM + 255) / 256, 256, 0, stream>>>(t2, nW2, nb2, out, G);
}

// Round 8
// 717.101 us; speedup vs baseline: 2.1114x; 1.0006x over previous
//
#include <hip/hip_runtime.h>
#include <hip/hip_bf16.h>
#include <math.h>

#define NODE_DIM 64
#define EDGE_DIM 32
#define HIDDEN   128
#define OUT_DIM  32
#define N_LAYERS 3
#define NGRAPH   128

typedef __attribute__((ext_vector_type(8))) short bf16x8;
typedef __attribute__((ext_vector_type(4))) float f32x4;

__device__ __forceinline__ unsigned short f2bf(float f) {
    unsigned u = __float_as_uint(f);
    u = (u + 0x7fffu + ((u >> 16) & 1u)) >> 16;
    return (unsigned short)u;
}
__device__ __forceinline__ float bf2f(unsigned short h) {
    return __uint_as_float((unsigned)h << 16);
}
// HW pair-convert f32x2 -> packed bf16x2 (RNE, same as f2bf) — v_cvt_pk_bf16_f32
__device__ __forceinline__ unsigned pkbf(float lo, float hi) {
    __hip_bfloat162 t = __float22bfloat162_rn(make_float2(lo, hi));
    return *reinterpret_cast<unsigned*>(&t);
}
// tanh(x) = 2/(1+exp(-2x)) - 1 : saturates correctly at +/-1, no abs/copysign
__device__ __forceinline__ float fast_tanh(float x) {
    float e = __expf(-2.f * x);
    float r = __builtin_amdgcn_rcpf(1.f + e);
    return __builtin_fmaf(2.f, r, -1.f);
}

// ---------------------------------------------------------------------------
// Two-level counting sort of edges by target node — LDS atomics only.
// ---------------------------------------------------------------------------
__global__ __launch_bounds__(256) void coarse_hist_kernel(
    const int* __restrict__ tgt, int* __restrict__ Hc, int E, int C, int NB) {
    __shared__ int lh[512];
    int blk = blockIdx.x, tid = threadIdx.x;
    for (int b = tid; b < C; b += 256) lh[b] = 0;
    __syncthreads();
    int base = blk * 4096;
#pragma unroll
    for (int i = 0; i < 16; ++i) {
        int e = base + i * 256 + tid;
        if (e < E) atomicAdd(&lh[tgt[e] >> 7], 1);
    }
    __syncthreads();
    for (int b = tid; b < C; b += 256) Hc[(size_t)b * NB + blk] = lh[b];
}

__global__ __launch_bounds__(256) void scan1_kernel(const int* __restrict__ c,
                                                    int* __restrict__ o,
                                                    int* __restrict__ bsum, int n) {
    __shared__ int sh[256];
    int b = blockIdx.x, t = threadIdx.x;
    int i = b * 256 + t;
    int v = (i < n) ? c[i] : 0;
    sh[t] = v;
    __syncthreads();
    for (int d = 1; d < 256; d <<= 1) {
        int u = (t >= d) ? sh[t - d] : 0;
        __syncthreads();
        sh[t] += u;
        __syncthreads();
    }
    if (i < n) o[i] = sh[t] - v;          // exclusive within block
    if (t == 255) bsum[b] = sh[255];      // block total
}

__global__ void scan2_kernel(int* __restrict__ bsum, int nb) {
    __shared__ int sh[1024];
    int t = threadIdx.x;
    int v = (t < nb) ? bsum[t] : 0;
    sh[t] = v;
    __syncthreads();
    for (int d = 1; d < 1024; d <<= 1) {
        int u = (t >= d) ? sh[t - d] : 0;
        __syncthreads();
        sh[t] += u;
        __syncthreads();
    }
    if (t < nb) bsum[t] = sh[t] - v;      // exclusive block offsets
}

__global__ __launch_bounds__(256) void scan3_kernel(int* __restrict__ o,
                                                    const int* __restrict__ bsum, int n) {
    int i = blockIdx.x * 256 + threadIdx.x;
    if (i < n) o[i] += bsum[blockIdx.x];
}

__global__ __launch_bounds__(256) void coarse_scatter_kernel(
    const int* __restrict__ tgt, const int* __restrict__ Sc,
    int* __restrict__ tgtc, int* __restrict__ ec, int E, int C, int NB) {
    __shared__ int lb[512];
    int blk = blockIdx.x, tid = threadIdx.x;
    for (int b = tid; b < C; b += 256) lb[b] = Sc[(size_t)b * NB + blk];
    __syncthreads();
    int base = blk * 4096;
#pragma unroll
    for (int i = 0; i < 16; ++i) {
        int e = base + i * 256 + tid;
        if (e < E) {
            int t = tgt[e];
            int pos = atomicAdd(&lb[t >> 7], 1);
            tgtc[pos] = t;
            ec[pos] = e;
        }
    }
}

// One block per coarse bucket: fine 128-bin sort + off[] emission.
__global__ __launch_bounds__(256) void fine_sort_kernel(
    const int* __restrict__ Sc, const int* __restrict__ tgtc,
    const int* __restrict__ ec, const int* __restrict__ src,
    int* __restrict__ off, int* __restrict__ eidx, int* __restrict__ srcp,
    int E, int N, int C, int NB) {
    __shared__ int fh[128], fs[128], rb[128];
    int b = blockIdx.x, tid = threadIdx.x;
    int cb0 = Sc[(size_t)b * NB];
    int cb1 = (b + 1 < C) ? Sc[(size_t)(b + 1) * NB] : E;
    if (tid < 128) fh[tid] = 0;
    __syncthreads();
    for (int p = cb0 + tid; p < cb1; p += 256) atomicAdd(&fh[tgtc[p] & 127], 1);
    __syncthreads();
    if (tid < 128) fs[tid] = fh[tid];
    __syncthreads();
    for (int d = 1; d < 128; d <<= 1) {
        int v = 0;
        if (tid < 128 && tid >= d) v = fs[tid - d];
        __syncthreads();
        if (tid < 128) fs[tid] += v;
        __syncthreads();
    }
    if (tid < 128) {
        int ex = fs[tid] - fh[tid];  // exclusive base within bucket
        rb[tid] = ex;
        int node = (b << 7) + tid;
        if (node < N) off[node] = cb0 + ex;
    }
    if (b == C - 1 && tid == 0) off[N] = E;
    __syncthreads();
    for (int p = cb0 + tid; p < cb1; p += 256) {
        int t = tgtc[p];
        int r = atomicAdd(&rb[t & 127], 1);
        int fpos = cb0 + r;
        int e = ec[p];
        eidx[fpos] = e;
        srcp[fpos] = src[e];
    }
}

// batch is sorted: mark graph boundaries directly
__global__ void gbound_kernel(const int* __restrict__ batch, int* __restrict__ goff,
                              int N, int G) {
    int i = blockIdx.x * 256 + threadIdx.x;
    if (i >= N) return;
    int b = batch[i];
    if (i == 0) {
        for (int g = 0; g <= b; ++g) goff[g] = 0;
    } else {
        int bp = batch[i - 1];
        for (int g = bp + 1; g <= b; ++g) goff[g] = i;
    }
    if (i == N - 1) {
        for (int g = b + 1; g <= G; ++g) goff[g] = N;
    }
}

// ---------------------------------------------------------------------------
// Permute+convert edge_attr to bf16 in target-sorted order (coalesced writes)
// ---------------------------------------------------------------------------
__global__ __launch_bounds__(256) void perm_ea_kernel(
    const float* __restrict__ ea, const int* __restrict__ eidx,
    unsigned short* __restrict__ out, int E) {
    int p = blockIdx.x * 256 + threadIdx.x;
    if (p >= E) return;
    int e = eidx[p];
    const float4* r = (const float4*)(ea + (size_t)e * EDGE_DIM);
    union { unsigned short us[EDGE_DIM]; uint4 u4[EDGE_DIM / 8]; } tmp;
#pragma unroll
    for (int q = 0; q < EDGE_DIM / 4; ++q) {
        float4 v = r[q];
        tmp.us[4 * q]     = f2bf(v.x);
        tmp.us[4 * q + 1] = f2bf(v.y);
        tmp.us[4 * q + 2] = f2bf(v.z);
        tmp.us[4 * q + 3] = f2bf(v.w);
    }
    uint4* o = (uint4*)(out + (size_t)p * EDGE_DIM);
#pragma unroll
    for (int k = 0; k < EDGE_DIM / 8; ++k) o[k] = tmp.u4[k];
}

// ---------------------------------------------------------------------------
// Parallel weight swizzle into MFMA A-frag order: one block per 16x32 tile.
// ---------------------------------------------------------------------------
__global__ void swizzle_w_kernel(const float* __restrict__ fW1, const float* __restrict__ fW2,
                                 const float* __restrict__ oW1, const float* __restrict__ oW2,
                                 unsigned short* __restrict__ W1sw, unsigned short* __restrict__ W2sw,
                                 unsigned short* __restrict__ oW1sw, unsigned short* __restrict__ oW2sw) {
    int i = blockIdx.x / 56, r = blockIdx.x % 56;
    int L = threadIdx.x;
    int e = L & 15, q = L >> 4;
    const float* W;
    unsigned short* out;
    int K, M, t;
    if (r < 8)       { W = fW1 + (size_t)i * EDGE_DIM * HIDDEN;  out = W1sw  + (size_t)i * 8 * 512;  K = EDGE_DIM; M = HIDDEN;   t = r; }
    else if (r < 24) { W = fW2 + (size_t)i * HIDDEN * NODE_DIM;  out = W2sw  + (size_t)i * 16 * 512; K = HIDDEN;   M = NODE_DIM; t = r - 8; }
    else if (r < 40) { W = oW1 + (size_t)i * NODE_DIM * HIDDEN;  out = oW1sw + (size_t)i * 16 * 512; K = NODE_DIM; M = HIDDEN;   t = r - 24; }
    else             { W = oW2 + (size_t)i * HIDDEN * NODE_DIM;  out = oW2sw + (size_t)i * 16 * 512; K = HIDDEN;   M = NODE_DIM; t = r - 40; }
    int nc = K >> 5;
    int mt = t / nc, s = t - mt * nc;
    union { unsigned short us[8]; uint4 u4; } pk;
#pragma unroll
    for (int j = 0; j < 8; ++j)
        pk.us[j] = f2bf(W[(size_t)(32 * s + 8 * q + j) * M + 16 * mt + e]);
    *(uint4*)(out + ((size_t)t * 64 + L) * 8) = pk.u4;
}

#define HSTRIDE 136  // shorts; 128 + 8 pad, keeps 16B alignment for ds_read_b128

// ---------------------------------------------------------------------------
// MFMA edge kernel: wave per 32 edges, two 16-edge groups A/B interleaved
// per weight fragment. HW bf16 pair-converts in the hot loops; wexp stores
// the already-exponentiated softmax weight.
// ---------------------------------------------------------------------------
__global__ __launch_bounds__(256, 4) void edge_mfma_kernel(
    const unsigned short* __restrict__ ea_p, const float* __restrict__ hd,
    const unsigned short* __restrict__ W1sw, const float* __restrict__ b1,
    const unsigned short* __restrict__ W2sw, const float* __restrict__ b2,
    const float* __restrict__ av, const int* __restrict__ srcp,
    unsigned short* __restrict__ msg, float* __restrict__ wexp, int E) {
    __shared__ unsigned short Hl[4][2][16 * HSTRIDE];
    int wave = threadIdx.x >> 6, lane = threadIdx.x & 63;
    int e = lane & 15, q = lane >> 4;
    int p0 = blockIdx.x * 128 + wave * 32;
    if (p0 >= E) return;   // no barriers below: safe
    int pA = p0 + e, pB = p0 + 16 + e;
    int pAc = pA < E ? pA : E - 1;
    int pBc = pB < E ? pB : E - 1;
    bool vA = pA < E, vB = pB < E;

    bf16x8 eafA = *(const bf16x8*)(ea_p + (size_t)pAc * EDGE_DIM + q * 8);
    bf16x8 eafB = *(const bf16x8*)(ea_p + (size_t)pBc * EDGE_DIM + q * 8);
    int sA = srcp[pAc];
    int sB = srcp[pBc];
    unsigned short* hrA = &Hl[wave][0][e * HSTRIDE];
    unsigned short* hrB = &Hl[wave][1][e * HSTRIDE];

    // ---- phase 1: per-tile {load W1 frag, MFMA x2, tanh x2, LDS write x2} ----
#pragma unroll
    for (int t = 0; t < 8; ++t) {
        bf16x8 a = *(const bf16x8*)(W1sw + (t * 64 + lane) * 8);
        f32x4 cA = __builtin_amdgcn_mfma_f32_16x16x32_bf16(a, eafA, (f32x4){0.f, 0.f, 0.f, 0.f}, 0, 0, 0);
        f32x4 cB = __builtin_amdgcn_mfma_f32_16x16x32_bf16(a, eafB, (f32x4){0.f, 0.f, 0.f, 0.f}, 0, 0, 0);
        float4 b = *(const float4*)(b1 + 16 * t + 4 * q);
        {
            uint2 pk;
            pk.x = pkbf(fast_tanh(cA[0] + b.x), fast_tanh(cA[1] + b.y));
            pk.y = pkbf(fast_tanh(cA[2] + b.z), fast_tanh(cA[3] + b.w));
            *(uint2*)(hrA + 16 * t + 4 * q) = pk;  // ds_write_b64
        }
        {
            uint2 pk;
            pk.x = pkbf(fast_tanh(cB[0] + b.x), fast_tanh(cB[1] + b.y));
            pk.y = pkbf(fast_tanh(cB[2] + b.z), fast_tanh(cB[3] + b.w));
            *(uint2*)(hrB + 16 * t + 4 * q) = pk;
        }
    }

    // ---- phase 2: np-halves; hd gathers issued inside, used after 8 MFMAs ----
    float scA = 0.f, scB = 0.f;
#pragma unroll
    for (int np = 0; np < 2; ++np) {
        float4 hvA[2], hvB[2];
#pragma unroll
        for (int k = 0; k < 2; ++k) {
            hvA[k] = *(const float4*)(hd + (size_t)sA * NODE_DIM + 16 * (2 * np + k) + 4 * q);
            hvB[k] = *(const float4*)(hd + (size_t)sB * NODE_DIM + 16 * (2 * np + k) + 4 * q);
        }
        f32x4 c2A[2] = {{0.f, 0.f, 0.f, 0.f}, {0.f, 0.f, 0.f, 0.f}};
        f32x4 c2B[2] = {{0.f, 0.f, 0.f, 0.f}, {0.f, 0.f, 0.f, 0.f}};
#pragma unroll
        for (int s = 0; s < 4; ++s) {
            bf16x8 hfA = *(const bf16x8*)(hrA + 32 * s + 8 * q);
            bf16x8 hfB = *(const bf16x8*)(hrB + 32 * s + 8 * q);
            bf16x8 a0 = *(const bf16x8*)(W2sw + (((2 * np + 0) * 4 + s) * 64 + lane) * 8);
            bf16x8 a1 = *(const bf16x8*)(W2sw + (((2 * np + 1) * 4 + s) * 64 + lane) * 8);
            c2A[0] = __builtin_amdgcn_mfma_f32_16x16x32_bf16(a0, hfA, c2A[0], 0, 0, 0);
            c2B[0] = __builtin_amdgcn_mfma_f32_16x16x32_bf16(a0, hfB, c2B[0], 0, 0, 0);
            c2A[1] = __builtin_amdgcn_mfma_f32_16x16x32_bf16(a1, hfA, c2A[1], 0, 0, 0);
            c2B[1] = __builtin_amdgcn_mfma_f32_16x16x32_bf16(a1, hfB, c2B[1], 0, 0, 0);
        }
#pragma unroll
        for (int k = 0; k < 2; ++k) {
            int nt = 2 * np + k;
            float4 bb = *(const float4*)(b2 + 16 * nt + 4 * q);
            float4 vv = *(const float4*)(av + 16 * nt + 4 * q);
            {
                float4 hh = hvA[k];
                float m0 = (c2A[k][0] + bb.x) * hh.x;
                float m1 = (c2A[k][1] + bb.y) * hh.y;
                float m2 = (c2A[k][2] + bb.z) * hh.z;
                float m3 = (c2A[k][3] + bb.w) * hh.w;
                uint2 pk;
                pk.x = pkbf(m0, m1);
                pk.y = pkbf(m2, m3);
                if (vA) *(uint2*)(msg + (size_t)pA * NODE_DIM + 16 * nt + 4 * q) = pk;
                scA += m0 * vv.x + m1 * vv.y + m2 * vv.z + m3 * vv.w;
            }
            {
                float4 hh = hvB[k];
                float m0 = (c2B[k][0] + bb.x) * hh.x;
                float m1 = (c2B[k][1] + bb.y) * hh.y;
                float m2 = (c2B[k][2] + bb.z) * hh.z;
                float m3 = (c2B[k][3] + bb.w) * hh.w;
                uint2 pk;
                pk.x = pkbf(m0, m1);
                pk.y = pkbf(m2, m3);
                if (vB) *(uint2*)(msg + (size_t)pB * NODE_DIM + 16 * nt + 4 * q) = pk;
                scB += m0 * vv.x + m1 * vv.y + m2 * vv.z + m3 * vv.w;
            }
        }
    }
    scA += __shfl_xor(scA, 16, 64);
    scA += __shfl_xor(scA, 32, 64);
    scB += __shfl_xor(scB, 16, 64);
    scB += __shfl_xor(scB, 32, 64);
    if (q == 0) {
        if (vA) wexp[pA] = __expf(fminf(scA, 60.f));
        if (vB) wexp[pB] = __expf(fminf(scB, 60.f));
    }
}

// ---------------------------------------------------------------------------
// FUSED aggregation + node out-MLP. Block = 4 waves x 16 nodes = 64 nodes.
// Each wave: (a) aggregate its 16 nodes into wave-private LDS (f32 rows),
// (b) read rows as MFMA B-frags, (c) reuse the SAME LDS region for the
// hidden bf16 stage, (d) MFMA out-MLP, h += delta. agg[] never hits HBM.
// BARRIER-SAFE: every wave reaches the single __syncthreads (no early return
// before it); tail LDS rows zero-filled so no uninitialized data enters MFMA.
// ---------------------------------------------------------------------------
__global__ __launch_bounds__(256) void agg_mlp_kernel(
    const unsigned short* __restrict__ msg, const float* __restrict__ wexp,
    const int* __restrict__ off,
    const unsigned short* __restrict__ W1sw, const float* __restrict__ b1,
    const unsigned short* __restrict__ W2sw, const float* __restrict__ b2,
    float* __restrict__ h, int N) {
    __shared__ float S[4][16 * 68];   // 4352 B/wave: agg rows f32, then H bf16
    int wave = threadIdx.x >> 6, lane = threadIdx.x & 63;
    int n0 = blockIdx.x * 64 + wave * 16;
    bool active = n0 < N;
    int g = lane >> 3, s = lane & 7;
    int e = lane & 15, q = lane >> 4;
    float* Sw = &S[wave][0];
    bf16x8 bfr[2] = {};

    if (active) {
        int offv = 0;
        if (lane < 17) {
            int idx = n0 + lane;
            offv = off[idx < N ? idx : N];
        }
        int imax = (N - n0 < 16) ? (N - n0) : 16;
        // zero-fill tail rows (last block only) so B-frag reads are defined
        if (g == 0) {
            float4 z = {0.f, 0.f, 0.f, 0.f};
            for (int i = imax; i < 16; ++i) {
                *(float4*)(Sw + i * 68 + s * 8) = z;
                *(float4*)(Sw + i * 68 + s * 8 + 4) = z;
            }
        }
        for (int i = 0; i < imax; ++i) {
            int o0 = __shfl(offv, i, 64);
            int o1 = __shfl(offv, i + 1, 64);
            float den = 0.f;
            float acc[8] = {0.f, 0.f, 0.f, 0.f, 0.f, 0.f, 0.f, 0.f};
            for (int p = o0; p < o1; p += 8) {
                int pe = p + g;
                int pc = (pe < o1) ? pe : (o1 - 1);
                float w = (pe < o1) ? wexp[pc] : 0.f;
                den += w;
                union { bf16x8 v; unsigned short us[8]; } eu;
                eu.v = *(const bf16x8*)(msg + (size_t)pc * NODE_DIM + s * 8);
                acc[0] += w * bf2f(eu.us[0]);
                acc[1] += w * bf2f(eu.us[1]);
                acc[2] += w * bf2f(eu.us[2]);
                acc[3] += w * bf2f(eu.us[3]);
                acc[4] += w * bf2f(eu.us[4]);
                acc[5] += w * bf2f(eu.us[5]);
                acc[6] += w * bf2f(eu.us[6]);
                acc[7] += w * bf2f(eu.us[7]);
            }
#pragma unroll
            for (int j = 0; j < 8; ++j) {
                acc[j] += __shfl_xor(acc[j], 8, 64);
                acc[j] += __shfl_xor(acc[j], 16, 64);
                acc[j] += __shfl_xor(acc[j], 32, 64);
            }
            den += __shfl_xor(den, 8, 64);
            den += __shfl_xor(den, 16, 64);
            den += __shfl_xor(den, 32, 64);
            if (g == 0) {
                float inv = 0.f;
                if (o1 > o0) {
                    inv = __builtin_amdgcn_rcpf(den);
                    inv = inv * (2.f - den * inv);
                }
                float4 r0 = {acc[0] * inv, acc[1] * inv, acc[2] * inv, acc[3] * inv};
                float4 r1 = {acc[4] * inv, acc[5] * inv, acc[6] * inv, acc[7] * inv};
                *(float4*)(Sw + i * 68 + s * 8) = r0;
                *(float4*)(Sw + i * 68 + s * 8 + 4) = r1;
            }
        }

        // ---- read agg rows as B-frags (before LDS region is reused for H) ----
#pragma unroll
        for (int sp = 0; sp < 2; ++sp) {
            float4 x0 = *(const float4*)(Sw + e * 68 + 32 * sp + 8 * q);
            float4 x1 = *(const float4*)(Sw + e * 68 + 32 * sp + 8 * q + 4);
            union { bf16x8 v; unsigned u[4]; } u;
            u.u[0] = pkbf(x0.x, x0.y);
            u.u[1] = pkbf(x0.z, x0.w);
            u.u[2] = pkbf(x1.x, x1.y);
            u.u[3] = pkbf(x1.z, x1.w);
            bfr[sp] = u.v;
        }
    }
    __syncthreads();   // all waves reach this; aliasing fence for Sw reuse
    if (!active) return;

    int ne = n0 + e;
    bool ok = ne < N;

    f32x4 c1[8];
#pragma unroll
    for (int t = 0; t < 8; ++t) {
        bf16x8 a0 = *(const bf16x8*)(W1sw + ((t * 2 + 0) * 64 + lane) * 8);
        bf16x8 a1 = *(const bf16x8*)(W1sw + ((t * 2 + 1) * 64 + lane) * 8);
        c1[t] = __builtin_amdgcn_mfma_f32_16x16x32_bf16(a0, bfr[0], (f32x4){0.f, 0.f, 0.f, 0.f}, 0, 0, 0);
        c1[t] = __builtin_amdgcn_mfma_f32_16x16x32_bf16(a1, bfr[1], c1[t], 0, 0, 0);
    }

    unsigned short* hrow = (unsigned short*)Sw + e * HSTRIDE;
#pragma unroll
    for (int t = 0; t < 8; ++t) {
        float4 b = *(const float4*)(b1 + 16 * t + 4 * q);
        uint2 pk;
        pk.x = pkbf(fast_tanh(c1[t][0] + b.x), fast_tanh(c1[t][1] + b.y));
        pk.y = pkbf(fast_tanh(c1[t][2] + b.z), fast_tanh(c1[t][3] + b.w));
        *(uint2*)(hrow + 16 * t + 4 * q) = pk;
    }

    f32x4 c2[4] = {{0.f, 0.f, 0.f, 0.f}, {0.f, 0.f, 0.f, 0.f},
                   {0.f, 0.f, 0.f, 0.f}, {0.f, 0.f, 0.f, 0.f}};
#pragma unroll
    for (int sp = 0; sp < 4; ++sp) {
        bf16x8 hf = *(const bf16x8*)(hrow + 32 * sp + 8 * q);
#pragma unroll
        for (int nt = 0; nt < 4; ++nt) {
            bf16x8 a = *(const bf16x8*)(W2sw + ((nt * 4 + sp) * 64 + lane) * 8);
            c2[nt] = __builtin_amdgcn_mfma_f32_16x16x32_bf16(a, hf, c2[nt], 0, 0, 0);
        }
    }

    if (ok) {
#pragma unroll
        for (int nt = 0; nt < 4; ++nt) {
            float4 bb = *(const float4*)(b2 + 16 * nt + 4 * q);
            float4* hp = (float4*)(h + (size_t)ne * NODE_DIM + 16 * nt + 4 * q);
            float4 hv = *hp;
            hv.x += c2[nt][0] + bb.x;
            hv.y += c2[nt][1] + bb.y;
            hv.z += c2[nt][2] + bb.z;
            hv.w += c2[nt][3] + bb.w;
            *hp = hv;
        }
    }
}

// ---------------------------------------------------------------------------
// Generic dense layer (fp32): hd and final output MLP
// ---------------------------------------------------------------------------
template <int K, int M, bool ACT, bool RESID>
__global__ __launch_bounds__(256) void dense_kernel(
    const float* __restrict__ X, const float* __restrict__ W,
    const float* __restrict__ bias, float* __restrict__ Y, int rows) {
    int tid = blockIdx.x * 256 + threadIdx.x;
    int row = tid / M;
    int d = tid - row * M;
    if (row >= rows) return;
    if (M >= 64) row = __builtin_amdgcn_readfirstlane(row);
    const float* __restrict__ x = X + (size_t)row * K;
    float acc = bias ? bias[d] : 0.f;
#pragma unroll
    for (int k = 0; k < K; ++k) acc += x[k] * W[k * M + d];
    if (ACT) acc = fast_tanh(acc);
    if (RESID) acc += Y[(size_t)row * M + d];
    Y[(size_t)row * M + d] = acc;
}

// ---------------------------------------------------------------------------
// Mean pool per graph: 4 waves per graph + LDS reduce
// ---------------------------------------------------------------------------
__global__ __launch_bounds__(256) void pool_kernel(const float* __restrict__ h,
                                                   const int* __restrict__ goff,
                                                   float* __restrict__ pooled) {
    __shared__ float sh[4][NODE_DIM];
    int g = blockIdx.x;
    int w = threadIdx.x >> 6, d = threadIdx.x & 63;
    int o0 = goff[g], o1 = goff[g + 1];
    float acc = 0.f;
    for (int n = o0 + w; n < o1; n += 4) acc += h[(size_t)n * NODE_DIM + d];
    sh[w][d] = acc;
    __syncthreads();
    if (w == 0) {
        float sum = sh[0][d] + sh[1][d] + sh[2][d] + sh[3][d];
        int c = o1 - o0;
        if (c < 1) c = 1;
        pooled[g * NODE_DIM + d] = sum / (float)c;
    }
}

// ---------------------------------------------------------------------------
extern "C" void kernel_launch(void* const* d_in, const int* in_sizes, int n_in,
                              void* d_out, int out_size, void* d_ws, size_t ws_size,
                              hipStream_t stream) {
    const float* x         = (const float*)d_in[0];
    const float* edge_attr = (const float*)d_in[1];
    const int*   ei        = (const int*)d_in[2];
    const int*   batch     = (const int*)d_in[3];
    const float* Wd        = (const float*)d_in[4];
    const float* fW1       = (const float*)d_in[5];
    const float* fb1       = (const float*)d_in[6];
    const float* fW2       = (const float*)d_in[7];
    const float* fb2       = (const float*)d_in[8];
    const float* av        = (const float*)d_in[9];
    const float* oW1       = (const float*)d_in[10];
    const float* ob1       = (const float*)d_in[11];
    const float* oW2       = (const float*)d_in[12];
    const float* ob2       = (const float*)d_in[13];
    const float* nW1       = (const float*)d_in[14];
    const float* nb1       = (const float*)d_in[15];
    const float* nW2       = (const float*)d_in[16];
    const float* nb2       = (const float*)d_in[17];
    float* out = (float*)d_out;

    const int N = in_sizes[0] / NODE_DIM;   // 50000
    const int E = in_sizes[2] / 2;          // 800000
    const int G = NGRAPH;
    const int NB = (E + 4095) / 4096;       // coarse blocks (196)
    const int C  = (N + 127) >> 7;          // coarse buckets (391)
    const int SN = C * NB;                  // scan length (76636)
    const int SB = (SN + 255) / 256;        // scan blocks (300, must be <=1024)

    char* base = (char*)d_ws;
    size_t pos = 0;
    auto alloc = [&](size_t bytes) -> void* {
        pos = (pos + 255) & ~(size_t)255;
        void* r = base + pos;
        pos += bytes;
        return r;
    };
    int* Hc   = (int*)alloc((size_t)SN * 4);
    int* Sc   = (int*)alloc(((size_t)SN + 1) * 4);
    int* bsum = (int*)alloc((size_t)1024 * 4);
    int* tgtc = (int*)alloc((size_t)E * 4);
    int* ec   = (int*)alloc((size_t)E * 4);
    int* off  = (int*)alloc((size_t)(N + 1) * 4);
    int* goff = (int*)alloc((size_t)(G + 1) * 4);
    int* eidx = (int*)alloc((size_t)E * 4);
    int* srcp = (int*)alloc((size_t)E * 4);
    float* wexp = (float*)alloc((size_t)E * 4);
    float* hd    = (float*)alloc((size_t)N * NODE_DIM * 4);
    float* h     = (float*)alloc((size_t)N * NODE_DIM * 4);
    float* pooled = (float*)alloc((size_t)G * NODE_DIM * 4);
    float* t2     = (float*)alloc((size_t)G * HIDDEN * 4);
    unsigned short* ea_p  = (unsigned short*)alloc((size_t)E * EDGE_DIM * 2);
    unsigned short* msg   = (unsigned short*)alloc((size_t)E * NODE_DIM * 2);
    unsigned short* W1sw  = (unsigned short*)alloc((size_t)N_LAYERS * 8 * 512 * 2);
    unsigned short* W2sw  = (unsigned short*)alloc((size_t)N_LAYERS * 16 * 512 * 2);
    unsigned short* oW1sw = (unsigned short*)alloc((size_t)N_LAYERS * 16 * 512 * 2);
    unsigned short* oW2sw = (unsigned short*)alloc((size_t)N_LAYERS * 16 * 512 * 2);
    (void)ws_size;

    const int* src = ei;
    const int* tgt = ei + E;

    // --- prep: two-level counting sort, hierarchical scan (no global atomics) ---
    coarse_hist_kernel<<<NB, 256, 0, stream>>>(tgt, Hc, E, C, NB);
    scan1_kernel<<<SB, 256, 0, stream>>>(Hc, Sc, bsum, SN);
    scan2_kernel<<<1, 1024, 0, stream>>>(bsum, SB);
    scan3_kernel<<<SB, 256, 0, stream>>>(Sc, bsum, SN);
    coarse_scatter_kernel<<<NB, 256, 0, stream>>>(tgt, Sc, tgtc, ec, E, C, NB);
    fine_sort_kernel<<<C, 256, 0, stream>>>(Sc, tgtc, ec, src, off, eidx, srcp, E, N, C, NB);
    gbound_kernel<<<(N + 255) / 256, 256, 0, stream>>>(batch, goff, N, G);
    perm_ea_kernel<<<(E + 255) / 256, 256, 0, stream>>>(edge_attr, eidx, ea_p, E);
    swizzle_w_kernel<<<N_LAYERS * 56, 64, 0, stream>>>(fW1, fW2, oW1, oW2, W1sw, W2sw, oW1sw, oW2sw);
    hipMemcpyAsync(h, x, (size_t)N * NODE_DIM * 4, hipMemcpyDeviceToDevice, stream);

    for (int i = 0; i < N_LAYERS; ++i) {
        dense_kernel<NODE_DIM, NODE_DIM, false, false>
            <<<(N * NODE_DIM + 255) / 256, 256, 0, stream>>>(
                h, Wd + (size_t)i * NODE_DIM * NODE_DIM, nullptr, hd, N);
        edge_mfma_kernel<<<(E + 127) / 128, 256, 0, stream>>>(
            ea_p, hd,
            W1sw + (size_t)i * 8 * 512, fb1 + (size_t)i * HIDDEN,
            W2sw + (size_t)i * 16 * 512, fb2 + (size_t)i * NODE_DIM,
            av + (size_t)i * NODE_DIM, srcp, msg, wexp, E);
        agg_mlp_kernel<<<(N + 63) / 64, 256, 0, stream>>>(
            msg, wexp, off,
            oW1sw + (size_t)i * 16 * 512, ob1 + (size_t)i * HIDDEN,
            oW2sw + (size_t)i * 16 * 512, ob2 + (size_t)i * NODE_DIM,
            h, N);
    }

    pool_kernel<<<G, 256, 0, stream>>>(h, goff, pooled);
    dense_kernel<NODE_DIM, HIDDEN, true, false>
        <<<(G * HIDDEN + 255) / 256, 256, 0, stream>>>(pooled, nW1, nb1, t2, G);
    dense_kernel<HIDDEN, OUT_DIM, false, false>
        <<<(G * OUT_DIM + 255) / 256, 256, 0, stream>>>(t2, nW2, nb2, out, G);
}

// Round 9
// 708.782 us; speedup vs baseline: 2.1362x; 1.0117x over previous
//
#include <hip/hip_runtime.h>
#include <hip/hip_bf16.h>
#include <math.h>

#define NODE_DIM 64
#define EDGE_DIM 32
#define HIDDEN   128
#define OUT_DIM  32
#define N_LAYERS 3
#define NGRAPH   128

typedef __attribute__((ext_vector_type(8))) short bf16x8;
typedef __attribute__((ext_vector_type(4))) float f32x4;

__device__ __forceinline__ unsigned short f2bf(float f) {
    unsigned u = __float_as_uint(f);
    u = (u + 0x7fffu + ((u >> 16) & 1u)) >> 16;
    return (unsigned short)u;
}
__device__ __forceinline__ float bf2f(unsigned short h) {
    return __uint_as_float((unsigned)h << 16);
}
// HW pair-convert f32x2 -> packed bf16x2 (RNE, same as f2bf) — v_cvt_pk_bf16_f32
__device__ __forceinline__ unsigned pkbf(float lo, float hi) {
    __hip_bfloat162 t = __float22bfloat162_rn(make_float2(lo, hi));
    return *reinterpret_cast<unsigned*>(&t);
}
// tanh(x) = 2/(1+exp(-2x)) - 1 : saturates correctly at +/-1, no abs/copysign
__device__ __forceinline__ float fast_tanh(float x) {
    float e = __expf(-2.f * x);
    float r = __builtin_amdgcn_rcpf(1.f + e);
    return __builtin_fmaf(2.f, r, -1.f);
}

// ---------------------------------------------------------------------------
// Two-level counting sort of edges by target node — LDS atomics only.
// ---------------------------------------------------------------------------
__global__ __launch_bounds__(256) void coarse_hist_kernel(
    const int* __restrict__ tgt, int* __restrict__ Hc, int E, int C, int NB) {
    __shared__ int lh[512];
    int blk = blockIdx.x, tid = threadIdx.x;
    for (int b = tid; b < C; b += 256) lh[b] = 0;
    __syncthreads();
    int base = blk * 4096;
#pragma unroll
    for (int i = 0; i < 16; ++i) {
        int e = base + i * 256 + tid;
        if (e < E) atomicAdd(&lh[tgt[e] >> 7], 1);
    }
    __syncthreads();
    for (int b = tid; b < C; b += 256) Hc[(size_t)b * NB + blk] = lh[b];
}

__global__ __launch_bounds__(256) void scan1_kernel(const int* __restrict__ c,
                                                    int* __restrict__ o,
                                                    int* __restrict__ bsum, int n) {
    __shared__ int sh[256];
    int b = blockIdx.x, t = threadIdx.x;
    int i = b * 256 + t;
    int v = (i < n) ? c[i] : 0;
    sh[t] = v;
    __syncthreads();
    for (int d = 1; d < 256; d <<= 1) {
        int u = (t >= d) ? sh[t - d] : 0;
        __syncthreads();
        sh[t] += u;
        __syncthreads();
    }
    if (i < n) o[i] = sh[t] - v;          // exclusive within block
    if (t == 255) bsum[b] = sh[255];      // block total
}

__global__ void scan2_kernel(int* __restrict__ bsum, int nb) {
    __shared__ int sh[1024];
    int t = threadIdx.x;
    int v = (t < nb) ? bsum[t] : 0;
    sh[t] = v;
    __syncthreads();
    for (int d = 1; d < 1024; d <<= 1) {
        int u = (t >= d) ? sh[t - d] : 0;
        __syncthreads();
        sh[t] += u;
        __syncthreads();
    }
    if (t < nb) bsum[t] = sh[t] - v;      // exclusive block offsets
}

// (scan3 eliminated: consumers add bsum[idx>>8] inline)

__global__ __launch_bounds__(256) void coarse_scatter_kernel(
    const int* __restrict__ tgt, const int* __restrict__ Sc,
    const int* __restrict__ bsum,
    int* __restrict__ tgtc, int* __restrict__ ec, int E, int C, int NB) {
    __shared__ int lb[512];
    int blk = blockIdx.x, tid = threadIdx.x;
    for (int b = tid; b < C; b += 256) {
        int idx = b * NB + blk;
        lb[b] = Sc[idx] + bsum[idx >> 8];
    }
    __syncthreads();
    int base = blk * 4096;
#pragma unroll
    for (int i = 0; i < 16; ++i) {
        int e = base + i * 256 + tid;
        if (e < E) {
            int t = tgt[e];
            int pos = atomicAdd(&lb[t >> 7], 1);
            tgtc[pos] = t;
            ec[pos] = e;
        }
    }
}

// One block per coarse bucket: fine 128-bin sort + off[] emission.
__global__ __launch_bounds__(256) void fine_sort_kernel(
    const int* __restrict__ Sc, const int* __restrict__ bsum,
    const int* __restrict__ tgtc,
    const int* __restrict__ ec, const int* __restrict__ src,
    int* __restrict__ off, int* __restrict__ eidx, int* __restrict__ srcp,
    int E, int N, int C, int NB) {
    __shared__ int fh[128], fs[128], rb[128];
    int b = blockIdx.x, tid = threadIdx.x;
    int i0 = b * NB;
    int cb0 = Sc[i0] + bsum[i0 >> 8];
    int cb1 = E;
    if (b + 1 < C) {
        int i1 = (b + 1) * NB;
        cb1 = Sc[i1] + bsum[i1 >> 8];
    }
    if (tid < 128) fh[tid] = 0;
    __syncthreads();
    for (int p = cb0 + tid; p < cb1; p += 256) atomicAdd(&fh[tgtc[p] & 127], 1);
    __syncthreads();
    if (tid < 128) fs[tid] = fh[tid];
    __syncthreads();
    for (int d = 1; d < 128; d <<= 1) {
        int v = 0;
        if (tid < 128 && tid >= d) v = fs[tid - d];
        __syncthreads();
        if (tid < 128) fs[tid] += v;
        __syncthreads();
    }
    if (tid < 128) {
        int ex = fs[tid] - fh[tid];  // exclusive base within bucket
        rb[tid] = ex;
        int node = (b << 7) + tid;
        if (node < N) off[node] = cb0 + ex;
    }
    if (b == C - 1 && tid == 0) off[N] = E;
    __syncthreads();
    for (int p = cb0 + tid; p < cb1; p += 256) {
        int t = tgtc[p];
        int r = atomicAdd(&rb[t & 127], 1);
        int fpos = cb0 + r;
        int e = ec[p];
        eidx[fpos] = e;
        srcp[fpos] = src[e];
    }
}

// batch is sorted: mark graph boundaries directly
__global__ void gbound_kernel(const int* __restrict__ batch, int* __restrict__ goff,
                              int N, int G) {
    int i = blockIdx.x * 256 + threadIdx.x;
    if (i >= N) return;
    int b = batch[i];
    if (i == 0) {
        for (int g = 0; g <= b; ++g) goff[g] = 0;
    } else {
        int bp = batch[i - 1];
        for (int g = bp + 1; g <= b; ++g) goff[g] = i;
    }
    if (i == N - 1) {
        for (int g = b + 1; g <= G; ++g) goff[g] = N;
    }
}

// ---------------------------------------------------------------------------
// Permute+convert edge_attr to bf16 in target-sorted order (coalesced writes)
// ---------------------------------------------------------------------------
__global__ __launch_bounds__(256) void perm_ea_kernel(
    const float* __restrict__ ea, const int* __restrict__ eidx,
    unsigned short* __restrict__ out, int E) {
    int p = blockIdx.x * 256 + threadIdx.x;
    if (p >= E) return;
    int e = eidx[p];
    const float4* r = (const float4*)(ea + (size_t)e * EDGE_DIM);
    union { unsigned short us[EDGE_DIM]; uint4 u4[EDGE_DIM / 8]; } tmp;
#pragma unroll
    for (int q = 0; q < EDGE_DIM / 4; ++q) {
        float4 v = r[q];
        tmp.us[4 * q]     = f2bf(v.x);
        tmp.us[4 * q + 1] = f2bf(v.y);
        tmp.us[4 * q + 2] = f2bf(v.z);
        tmp.us[4 * q + 3] = f2bf(v.w);
    }
    uint4* o = (uint4*)(out + (size_t)p * EDGE_DIM);
#pragma unroll
    for (int k = 0; k < EDGE_DIM / 8; ++k) o[k] = tmp.u4[k];
}

// ---------------------------------------------------------------------------
// Parallel weight swizzle into MFMA A-frag order: one block per 16x32 tile.
// ---------------------------------------------------------------------------
__global__ void swizzle_w_kernel(const float* __restrict__ fW1, const float* __restrict__ fW2,
                                 const float* __restrict__ oW1, const float* __restrict__ oW2,
                                 unsigned short* __restrict__ W1sw, unsigned short* __restrict__ W2sw,
                                 unsigned short* __restrict__ oW1sw, unsigned short* __restrict__ oW2sw) {
    int i = blockIdx.x / 56, r = blockIdx.x % 56;
    int L = threadIdx.x;
    int e = L & 15, q = L >> 4;
    const float* W;
    unsigned short* out;
    int K, M, t;
    if (r < 8)       { W = fW1 + (size_t)i * EDGE_DIM * HIDDEN;  out = W1sw  + (size_t)i * 8 * 512;  K = EDGE_DIM; M = HIDDEN;   t = r; }
    else if (r < 24) { W = fW2 + (size_t)i * HIDDEN * NODE_DIM;  out = W2sw  + (size_t)i * 16 * 512; K = HIDDEN;   M = NODE_DIM; t = r - 8; }
    else if (r < 40) { W = oW1 + (size_t)i * NODE_DIM * HIDDEN;  out = oW1sw + (size_t)i * 16 * 512; K = NODE_DIM; M = HIDDEN;   t = r - 24; }
    else             { W = oW2 + (size_t)i * HIDDEN * NODE_DIM;  out = oW2sw + (size_t)i * 16 * 512; K = HIDDEN;   M = NODE_DIM; t = r - 40; }
    int nc = K >> 5;
    int mt = t / nc, s = t - mt * nc;
    union { unsigned short us[8]; uint4 u4; } pk;
#pragma unroll
    for (int j = 0; j < 8; ++j)
        pk.us[j] = f2bf(W[(size_t)(32 * s + 8 * q + j) * M + 16 * mt + e]);
    *(uint4*)(out + ((size_t)t * 64 + L) * 8) = pk.u4;
}

#define HSTRIDE 136  // shorts; 128 + 8 pad, keeps 16B alignment for ds_read_b128

// ---------------------------------------------------------------------------
// MFMA edge kernel: wave per 32 edges, two 16-edge groups A/B interleaved
// per weight fragment. Cap (256,3): <=170 regs — enough headroom to avoid
// the r4 spill (WRITE_SIZE blowup) while keeping ~3 waves/SIMD occupancy.
// ---------------------------------------------------------------------------
__global__ __launch_bounds__(256, 3) void edge_mfma_kernel(
    const unsigned short* __restrict__ ea_p, const float* __restrict__ hd,
    const unsigned short* __restrict__ W1sw, const float* __restrict__ b1,
    const unsigned short* __restrict__ W2sw, const float* __restrict__ b2,
    const float* __restrict__ av, const int* __restrict__ srcp,
    unsigned short* __restrict__ msg, float* __restrict__ wexp, int E) {
    __shared__ unsigned short Hl[4][2][16 * HSTRIDE];
    int wave = threadIdx.x >> 6, lane = threadIdx.x & 63;
    int e = lane & 15, q = lane >> 4;
    int p0 = blockIdx.x * 128 + wave * 32;
    if (p0 >= E) return;   // no barriers below: safe
    int pA = p0 + e, pB = p0 + 16 + e;
    int pAc = pA < E ? pA : E - 1;
    int pBc = pB < E ? pB : E - 1;
    bool vA = pA < E, vB = pB < E;

    bf16x8 eafA = *(const bf16x8*)(ea_p + (size_t)pAc * EDGE_DIM + q * 8);
    bf16x8 eafB = *(const bf16x8*)(ea_p + (size_t)pBc * EDGE_DIM + q * 8);
    int sA = srcp[pAc];
    int sB = srcp[pBc];
    unsigned short* hrA = &Hl[wave][0][e * HSTRIDE];
    unsigned short* hrB = &Hl[wave][1][e * HSTRIDE];

    // ---- phase 1: per-tile {load W1 frag, MFMA x2, tanh x2, LDS write x2} ----
#pragma unroll
    for (int t = 0; t < 8; ++t) {
        bf16x8 a = *(const bf16x8*)(W1sw + (t * 64 + lane) * 8);
        f32x4 cA = __builtin_amdgcn_mfma_f32_16x16x32_bf16(a, eafA, (f32x4){0.f, 0.f, 0.f, 0.f}, 0, 0, 0);
        f32x4 cB = __builtin_amdgcn_mfma_f32_16x16x32_bf16(a, eafB, (f32x4){0.f, 0.f, 0.f, 0.f}, 0, 0, 0);
        float4 b = *(const float4*)(b1 + 16 * t + 4 * q);
        {
            uint2 pk;
            pk.x = pkbf(fast_tanh(cA[0] + b.x), fast_tanh(cA[1] + b.y));
            pk.y = pkbf(fast_tanh(cA[2] + b.z), fast_tanh(cA[3] + b.w));
            *(uint2*)(hrA + 16 * t + 4 * q) = pk;  // ds_write_b64
        }
        {
            uint2 pk;
            pk.x = pkbf(fast_tanh(cB[0] + b.x), fast_tanh(cB[1] + b.y));
            pk.y = pkbf(fast_tanh(cB[2] + b.z), fast_tanh(cB[3] + b.w));
            *(uint2*)(hrB + 16 * t + 4 * q) = pk;
        }
    }

    // ---- phase 2: np-halves; hd gathers issued inside, used after 8 MFMAs ----
    float scA = 0.f, scB = 0.f;
#pragma unroll
    for (int np = 0; np < 2; ++np) {
        float4 hvA[2], hvB[2];
#pragma unroll
        for (int k = 0; k < 2; ++k) {
            hvA[k] = *(const float4*)(hd + (size_t)sA * NODE_DIM + 16 * (2 * np + k) + 4 * q);
            hvB[k] = *(const float4*)(hd + (size_t)sB * NODE_DIM + 16 * (2 * np + k) + 4 * q);
        }
        f32x4 c2A[2] = {{0.f, 0.f, 0.f, 0.f}, {0.f, 0.f, 0.f, 0.f}};
        f32x4 c2B[2] = {{0.f, 0.f, 0.f, 0.f}, {0.f, 0.f, 0.f, 0.f}};
#pragma unroll
        for (int s = 0; s < 4; ++s) {
            bf16x8 hfA = *(const bf16x8*)(hrA + 32 * s + 8 * q);
            bf16x8 hfB = *(const bf16x8*)(hrB + 32 * s + 8 * q);
            bf16x8 a0 = *(const bf16x8*)(W2sw + (((2 * np + 0) * 4 + s) * 64 + lane) * 8);
            bf16x8 a1 = *(const bf16x8*)(W2sw + (((2 * np + 1) * 4 + s) * 64 + lane) * 8);
            c2A[0] = __builtin_amdgcn_mfma_f32_16x16x32_bf16(a0, hfA, c2A[0], 0, 0, 0);
            c2B[0] = __builtin_amdgcn_mfma_f32_16x16x32_bf16(a0, hfB, c2B[0], 0, 0, 0);
            c2A[1] = __builtin_amdgcn_mfma_f32_16x16x32_bf16(a1, hfA, c2A[1], 0, 0, 0);
            c2B[1] = __builtin_amdgcn_mfma_f32_16x16x32_bf16(a1, hfB, c2B[1], 0, 0, 0);
        }
#pragma unroll
        for (int k = 0; k < 2; ++k) {
            int nt = 2 * np + k;
            float4 bb = *(const float4*)(b2 + 16 * nt + 4 * q);
            float4 vv = *(const float4*)(av + 16 * nt + 4 * q);
            {
                float4 hh = hvA[k];
                float m0 = (c2A[k][0] + bb.x) * hh.x;
                float m1 = (c2A[k][1] + bb.y) * hh.y;
                float m2 = (c2A[k][2] + bb.z) * hh.z;
                float m3 = (c2A[k][3] + bb.w) * hh.w;
                uint2 pk;
                pk.x = pkbf(m0, m1);
                pk.y = pkbf(m2, m3);
                if (vA) *(uint2*)(msg + (size_t)pA * NODE_DIM + 16 * nt + 4 * q) = pk;
                scA += m0 * vv.x + m1 * vv.y + m2 * vv.z + m3 * vv.w;
            }
            {
                float4 hh = hvB[k];
                float m0 = (c2B[k][0] + bb.x) * hh.x;
                float m1 = (c2B[k][1] + bb.y) * hh.y;
                float m2 = (c2B[k][2] + bb.z) * hh.z;
                float m3 = (c2B[k][3] + bb.w) * hh.w;
                uint2 pk;
                pk.x = pkbf(m0, m1);
                pk.y = pkbf(m2, m3);
                if (vB) *(uint2*)(msg + (size_t)pB * NODE_DIM + 16 * nt + 4 * q) = pk;
                scB += m0 * vv.x + m1 * vv.y + m2 * vv.z + m3 * vv.w;
            }
        }
    }
    scA += __shfl_xor(scA, 16, 64);
    scA += __shfl_xor(scA, 32, 64);
    scB += __shfl_xor(scB, 16, 64);
    scB += __shfl_xor(scB, 32, 64);
    if (q == 0) {
        if (vA) wexp[pA] = __expf(fminf(scA, 60.f));
        if (vB) wexp[pB] = __expf(fminf(scB, 60.f));
    }
}

// ---------------------------------------------------------------------------
// FUSED aggregation + node out-MLP. Block = 4 waves x 16 nodes = 64 nodes.
// BARRIER-SAFE: every wave reaches the single __syncthreads; tail LDS rows
// zero-filled so no uninitialized data enters MFMA.
// ---------------------------------------------------------------------------
__global__ __launch_bounds__(256) void agg_mlp_kernel(
    const unsigned short* __restrict__ msg, const float* __restrict__ wexp,
    const int* __restrict__ off,
    const unsigned short* __restrict__ W1sw, const float* __restrict__ b1,
    const unsigned short* __restrict__ W2sw, const float* __restrict__ b2,
    float* __restrict__ h, int N) {
    __shared__ float S[4][16 * 68];   // 4352 B/wave: agg rows f32, then H bf16
    int wave = threadIdx.x >> 6, lane = threadIdx.x & 63;
    int n0 = blockIdx.x * 64 + wave * 16;
    bool active = n0 < N;
    int g = lane >> 3, s = lane & 7;
    int e = lane & 15, q = lane >> 4;
    float* Sw = &S[wave][0];
    bf16x8 bfr[2] = {};

    if (active) {
        int offv = 0;
        if (lane < 17) {
            int idx = n0 + lane;
            offv = off[idx < N ? idx : N];
        }
        int imax = (N - n0 < 16) ? (N - n0) : 16;
        // zero-fill tail rows (last block only) so B-frag reads are defined
        if (g == 0) {
            float4 z = {0.f, 0.f, 0.f, 0.f};
            for (int i = imax; i < 16; ++i) {
                *(float4*)(Sw + i * 68 + s * 8) = z;
                *(float4*)(Sw + i * 68 + s * 8 + 4) = z;
            }
        }
        for (int i = 0; i < imax; ++i) {
            int o0 = __shfl(offv, i, 64);
            int o1 = __shfl(offv, i + 1, 64);
            float den = 0.f;
            float acc[8] = {0.f, 0.f, 0.f, 0.f, 0.f, 0.f, 0.f, 0.f};
            for (int p = o0; p < o1; p += 8) {
                int pe = p + g;
                int pc = (pe < o1) ? pe : (o1 - 1);
                float w = (pe < o1) ? wexp[pc] : 0.f;
                den += w;
                union { bf16x8 v; unsigned short us[8]; } eu;
                eu.v = *(const bf16x8*)(msg + (size_t)pc * NODE_DIM + s * 8);
                acc[0] += w * bf2f(eu.us[0]);
                acc[1] += w * bf2f(eu.us[1]);
                acc[2] += w * bf2f(eu.us[2]);
                acc[3] += w * bf2f(eu.us[3]);
                acc[4] += w * bf2f(eu.us[4]);
                acc[5] += w * bf2f(eu.us[5]);
                acc[6] += w * bf2f(eu.us[6]);
                acc[7] += w * bf2f(eu.us[7]);
            }
#pragma unroll
            for (int j = 0; j < 8; ++j) {
                acc[j] += __shfl_xor(acc[j], 8, 64);
                acc[j] += __shfl_xor(acc[j], 16, 64);
                acc[j] += __shfl_xor(acc[j], 32, 64);
            }
            den += __shfl_xor(den, 8, 64);
            den += __shfl_xor(den, 16, 64);
            den += __shfl_xor(den, 32, 64);
            if (g == 0) {
                float inv = 0.f;
                if (o1 > o0) {
                    inv = __builtin_amdgcn_rcpf(den);
                    inv = inv * (2.f - den * inv);
                }
                float4 r0 = {acc[0] * inv, acc[1] * inv, acc[2] * inv, acc[3] * inv};
                float4 r1 = {acc[4] * inv, acc[5] * inv, acc[6] * inv, acc[7] * inv};
                *(float4*)(Sw + i * 68 + s * 8) = r0;
                *(float4*)(Sw + i * 68 + s * 8 + 4) = r1;
            }
        }

        // ---- read agg rows as B-frags (before LDS region is reused for H) ----
#pragma unroll
        for (int sp = 0; sp < 2; ++sp) {
            float4 x0 = *(const float4*)(Sw + e * 68 + 32 * sp + 8 * q);
            float4 x1 = *(const float4*)(Sw + e * 68 + 32 * sp + 8 * q + 4);
            union { bf16x8 v; unsigned u[4]; } u;
            u.u[0] = pkbf(x0.x, x0.y);
            u.u[1] = pkbf(x0.z, x0.w);
            u.u[2] = pkbf(x1.x, x1.y);
            u.u[3] = pkbf(x1.z, x1.w);
            bfr[sp] = u.v;
        }
    }
    __syncthreads();   // all waves reach this; aliasing fence for Sw reuse
    if (!active) return;

    int ne = n0 + e;
    bool ok = ne < N;

    f32x4 c1[8];
#pragma unroll
    for (int t = 0; t < 8; ++t) {
        bf16x8 a0 = *(const bf16x8*)(W1sw + ((t * 2 + 0) * 64 + lane) * 8);
        bf16x8 a1 = *(const bf16x8*)(W1sw + ((t * 2 + 1) * 64 + lane) * 8);
        c1[t] = __builtin_amdgcn_mfma_f32_16x16x32_bf16(a0, bfr[0], (f32x4){0.f, 0.f, 0.f, 0.f}, 0, 0, 0);
        c1[t] = __builtin_amdgcn_mfma_f32_16x16x32_bf16(a1, bfr[1], c1[t], 0, 0, 0);
    }

    unsigned short* hrow = (unsigned short*)Sw + e * HSTRIDE;
#pragma unroll
    for (int t = 0; t < 8; ++t) {
        float4 b = *(const float4*)(b1 + 16 * t + 4 * q);
        uint2 pk;
        pk.x = pkbf(fast_tanh(c1[t][0] + b.x), fast_tanh(c1[t][1] + b.y));
        pk.y = pkbf(fast_tanh(c1[t][2] + b.z), fast_tanh(c1[t][3] + b.w));
        *(uint2*)(hrow + 16 * t + 4 * q) = pk;
    }

    f32x4 c2[4] = {{0.f, 0.f, 0.f, 0.f}, {0.f, 0.f, 0.f, 0.f},
                   {0.f, 0.f, 0.f, 0.f}, {0.f, 0.f, 0.f, 0.f}};
#pragma unroll
    for (int sp = 0; sp < 4; ++sp) {
        bf16x8 hf = *(const bf16x8*)(hrow + 32 * sp + 8 * q);
#pragma unroll
        for (int nt = 0; nt < 4; ++nt) {
            bf16x8 a = *(const bf16x8*)(W2sw + ((nt * 4 + sp) * 64 + lane) * 8);
            c2[nt] = __builtin_amdgcn_mfma_f32_16x16x32_bf16(a, hf, c2[nt], 0, 0, 0);
        }
    }

    if (ok) {
#pragma unroll
        for (int nt = 0; nt < 4; ++nt) {
            float4 bb = *(const float4*)(b2 + 16 * nt + 4 * q);
            float4* hp = (float4*)(h + (size_t)ne * NODE_DIM + 16 * nt + 4 * q);
            float4 hv = *hp;
            hv.x += c2[nt][0] + bb.x;
            hv.y += c2[nt][1] + bb.y;
            hv.z += c2[nt][2] + bb.z;
            hv.w += c2[nt][3] + bb.w;
            *hp = hv;
        }
    }
}

// ---------------------------------------------------------------------------
// Generic dense layer (fp32): hd
// ---------------------------------------------------------------------------
template <int K, int M, bool ACT, bool RESID>
__global__ __launch_bounds__(256) void dense_kernel(
    const float* __restrict__ X, const float* __restrict__ W,
    const float* __restrict__ bias, float* __restrict__ Y, int rows) {
    int tid = blockIdx.x * 256 + threadIdx.x;
    int row = tid / M;
    int d = tid - row * M;
    if (row >= rows) return;
    if (M >= 64) row = __builtin_amdgcn_readfirstlane(row);
    const float* __restrict__ x = X + (size_t)row * K;
    float acc = bias ? bias[d] : 0.f;
#pragma unroll
    for (int k = 0; k < K; ++k) acc += x[k] * W[k * M + d];
    if (ACT) acc = fast_tanh(acc);
    if (RESID) acc += Y[(size_t)row * M + d];
    Y[(size_t)row * M + d] = acc;
}

// ---------------------------------------------------------------------------
// FUSED tail: mean pool per graph + 2-layer output MLP, one block per graph.
// Identical summation order to the previous pool + dense + dense kernels.
// ---------------------------------------------------------------------------
__global__ __launch_bounds__(256) void pool_net_kernel(
    const float* __restrict__ h, const int* __restrict__ goff,
    const float* __restrict__ nW1, const float* __restrict__ nb1,
    const float* __restrict__ nW2, const float* __restrict__ nb2,
    float* __restrict__ out) {
    __shared__ float sh[4][NODE_DIM];
    __shared__ float pooled[NODE_DIM];
    __shared__ float t2[HIDDEN];
    int g = blockIdx.x;
    int w = threadIdx.x >> 6, d = threadIdx.x & 63;
    int tid = threadIdx.x;
    int o0 = goff[g], o1 = goff[g + 1];
    float acc = 0.f;
    for (int n = o0 + w; n < o1; n += 4) acc += h[(size_t)n * NODE_DIM + d];
    sh[w][d] = acc;
    __syncthreads();
    if (w == 0) {
        float sum = sh[0][d] + sh[1][d] + sh[2][d] + sh[3][d];
        int c = o1 - o0;
        if (c < 1) c = 1;
        pooled[d] = sum / (float)c;
    }
    __syncthreads();
    if (tid < HIDDEN) {
        float a = nb1[tid];
#pragma unroll
        for (int k = 0; k < NODE_DIM; ++k) a += pooled[k] * nW1[k * HIDDEN + tid];
        t2[tid] = fast_tanh(a);
    }
    __syncthreads();
    if (tid < OUT_DIM) {
        float a = nb2[tid];
#pragma unroll
        for (int k = 0; k < HIDDEN; ++k) a += t2[k] * nW2[k * OUT_DIM + tid];
        out[g * OUT_DIM + tid] = a;
    }
}

// ---------------------------------------------------------------------------
extern "C" void kernel_launch(void* const* d_in, const int* in_sizes, int n_in,
                              void* d_out, int out_size, void* d_ws, size_t ws_size,
                              hipStream_t stream) {
    const float* x         = (const float*)d_in[0];
    const float* edge_attr = (const float*)d_in[1];
    const int*   ei        = (const int*)d_in[2];
    const int*   batch     = (const int*)d_in[3];
    const float* Wd        = (const float*)d_in[4];
    const float* fW1       = (const float*)d_in[5];
    const float* fb1       = (const float*)d_in[6];
    const float* fW2       = (const float*)d_in[7];
    const float* fb2       = (const float*)d_in[8];
    const float* av        = (const float*)d_in[9];
    const float* oW1       = (const float*)d_in[10];
    const float* ob1       = (const float*)d_in[11];
    const float* oW2       = (const float*)d_in[12];
    const float* ob2       = (const float*)d_in[13];
    const float* nW1       = (const float*)d_in[14];
    const float* nb1       = (const float*)d_in[15];
    const float* nW2       = (const float*)d_in[16];
    const float* nb2       = (const float*)d_in[17];
    float* out = (float*)d_out;

    const int N = in_sizes[0] / NODE_DIM;   // 50000
    const int E = in_sizes[2] / 2;          // 800000
    const int G = NGRAPH;
    const int NB = (E + 4095) / 4096;       // coarse blocks (196)
    const int C  = (N + 127) >> 7;          // coarse buckets (391)
    const int SN = C * NB;                  // scan length (76636)
    const int SB = (SN + 255) / 256;        // scan blocks (300, must be <=1024)

    char* base = (char*)d_ws;
    size_t pos = 0;
    auto alloc = [&](size_t bytes) -> void* {
        pos = (pos + 255) & ~(size_t)255;
        void* r = base + pos;
        pos += bytes;
        return r;
    };
    int* Hc   = (int*)alloc((size_t)SN * 4);
    int* Sc   = (int*)alloc(((size_t)SN + 1) * 4);
    int* bsum = (int*)alloc((size_t)1024 * 4);
    int* tgtc = (int*)alloc((size_t)E * 4);
    int* ec   = (int*)alloc((size_t)E * 4);
    int* off  = (int*)alloc((size_t)(N + 1) * 4);
    int* goff = (int*)alloc((size_t)(G + 1) * 4);
    int* eidx = (int*)alloc((size_t)E * 4);
    int* srcp = (int*)alloc((size_t)E * 4);
    float* wexp = (float*)alloc((size_t)E * 4);
    float* hd    = (float*)alloc((size_t)N * NODE_DIM * 4);
    float* h     = (float*)alloc((size_t)N * NODE_DIM * 4);
    unsigned short* ea_p  = (unsigned short*)alloc((size_t)E * EDGE_DIM * 2);
    unsigned short* msg   = (unsigned short*)alloc((size_t)E * NODE_DIM * 2);
    unsigned short* W1sw  = (unsigned short*)alloc((size_t)N_LAYERS * 8 * 512 * 2);
    unsigned short* W2sw  = (unsigned short*)alloc((size_t)N_LAYERS * 16 * 512 * 2);
    unsigned short* oW1sw = (unsigned short*)alloc((size_t)N_LAYERS * 16 * 512 * 2);
    unsigned short* oW2sw = (unsigned short*)alloc((size_t)N_LAYERS * 16 * 512 * 2);
    (void)ws_size;

    const int* src = ei;
    const int* tgt = ei + E;

    // --- prep: two-level counting sort, hierarchical scan (no global atomics) ---
    coarse_hist_kernel<<<NB, 256, 0, stream>>>(tgt, Hc, E, C, NB);
    scan1_kernel<<<SB, 256, 0, stream>>>(Hc, Sc, bsum, SN);
    scan2_kernel<<<1, 1024, 0, stream>>>(bsum, SB);
    coarse_scatter_kernel<<<NB, 256, 0, stream>>>(tgt, Sc, bsum, tgtc, ec, E, C, NB);
    fine_sort_kernel<<<C, 256, 0, stream>>>(Sc, bsum, tgtc, ec, src, off, eidx, srcp, E, N, C, NB);
    gbound_kernel<<<(N + 255) / 256, 256, 0, stream>>>(batch, goff, N, G);
    perm_ea_kernel<<<(E + 255) / 256, 256, 0, stream>>>(edge_attr, eidx, ea_p, E);
    swizzle_w_kernel<<<N_LAYERS * 56, 64, 0, stream>>>(fW1, fW2, oW1, oW2, W1sw, W2sw, oW1sw, oW2sw);
    hipMemcpyAsync(h, x, (size_t)N * NODE_DIM * 4, hipMemcpyDeviceToDevice, stream);

    for (int i = 0; i < N_LAYERS; ++i) {
        dense_kernel<NODE_DIM, NODE_DIM, false, false>
            <<<(N * NODE_DIM + 255) / 256, 256, 0, stream>>>(
                h, Wd + (size_t)i * NODE_DIM * NODE_DIM, nullptr, hd, N);
        edge_mfma_kernel<<<(E + 127) / 128, 256, 0, stream>>>(
            ea_p, hd,
            W1sw + (size_t)i * 8 * 512, fb1 + (size_t)i * HIDDEN,
            W2sw + (size_t)i * 16 * 512, fb2 + (size_t)i * NODE_DIM,
            av + (size_t)i * NODE_DIM, srcp, msg, wexp, E);
        agg_mlp_kernel<<<(N + 63) / 64, 256, 0, stream>>>(
            msg, wexp, off,
            oW1sw + (size_t)i * 16 * 512, ob1 + (size_t)i * HIDDEN,
            oW2sw + (size_t)i * 16 * 512, ob2 + (size_t)i * NODE_DIM,
            h, N);
    }

    pool_net_kernel<<<G, 256, 0, stream>>>(h, goff, nW1, nb1, nW2, nb2, out);
}